// Round 1
// baseline (1545.038 us; speedup 1.0000x reference)
//
#include <hip/hip_runtime.h>
#include <math.h>

#define N_NODES 50000
#define N_EDGES 800000
#define NGRAPH  64

// ===================== setup kernels =====================

__global__ __launch_bounds__(256) void node_enc_kernel(
    const float* __restrict__ xin, const float* __restrict__ nw,
    const float* __restrict__ nb, float* __restrict__ x)
{
  __shared__ float xs[256];
  int tid = threadIdx.x;
  int base = blockIdx.x * 256;          // 4 nodes per block
  xs[tid] = xin[base + tid];
  __syncthreads();
  int r = tid >> 6, j = tid & 63;
  float acc = nb[j];
#pragma unroll
  for (int t = 0; t < 64; t++) acc = fmaf(xs[r * 64 + t], nw[t * 64 + j], acc);
  x[base + tid] = acc;
}

__global__ void count_kernel(const int* __restrict__ dst, int* __restrict__ cnt)
{
  int e = blockIdx.x * 256 + threadIdx.x;   // grid exactly covers E
  atomicAdd(&cnt[dst[e]], 1);
}

__global__ __launch_bounds__(256) void scan_a_kernel(
    const int* __restrict__ cnt, int* __restrict__ bsum)
{
  __shared__ int s[256];
  int i = blockIdx.x * 256 + threadIdx.x;
  s[threadIdx.x] = (i < N_NODES) ? cnt[i] : 0;
  __syncthreads();
  for (int off = 128; off > 0; off >>= 1) {
    if (threadIdx.x < off) s[threadIdx.x] += s[threadIdx.x + off];
    __syncthreads();
  }
  if (threadIdx.x == 0) bsum[blockIdx.x] = s[0];
}

__global__ __launch_bounds__(256) void scan_b_kernel(
    const int* __restrict__ bsum, int* __restrict__ boff)
{
  __shared__ int s[256];
  int tid = threadIdx.x;
  int v = (tid < 196) ? bsum[tid] : 0;
  s[tid] = v;
  __syncthreads();
  for (int off = 1; off < 256; off <<= 1) {
    int t = (tid >= off) ? s[tid - off] : 0;
    __syncthreads();
    s[tid] += t;
    __syncthreads();
  }
  boff[tid] = s[tid] - v;   // exclusive prefix of block sums
}

__global__ __launch_bounds__(256) void scan_c_kernel(
    const int* __restrict__ cnt, const int* __restrict__ boff,
    int* __restrict__ row_ptr)
{
  __shared__ int s[256];
  int tid = threadIdx.x;
  int i = blockIdx.x * 256 + tid;
  int v = (i < N_NODES) ? cnt[i] : 0;
  s[tid] = v;
  __syncthreads();
  for (int off = 1; off < 256; off <<= 1) {
    int t = (tid >= off) ? s[tid - off] : 0;
    __syncthreads();
    s[tid] += t;
    __syncthreads();
  }
  int incl = s[tid];
  int base = boff[blockIdx.x];
  if (i < N_NODES) row_ptr[i] = base + incl - v;
  if (i == N_NODES - 1) row_ptr[N_NODES] = base + incl;
}

__global__ void fill_kernel(const int* __restrict__ src, const int* __restrict__ dst,
                            int* __restrict__ cursor, int2* __restrict__ pairs)
{
  int e = blockIdx.x * 256 + threadIdx.x;
  int d = dst[e];
  int pos = atomicAdd(&cursor[d], 1);
  pairs[pos] = make_int2(src[e], e);
}

__global__ __launch_bounds__(256) void deg_log_kernel(
    const int* __restrict__ cnt, float* __restrict__ log_deg,
    double* __restrict__ avgacc)
{
  __shared__ double sb[256];
  int i = blockIdx.x * 256 + threadIdx.x;
  double c = 0.0;
  if (i < N_NODES) {
    int d = cnt[i];
    int dc = d > 0 ? d : 1;
    log_deg[i] = logf((float)dc + 1.0f);         // log(degc + 1)
    c = (double)logf((float)d + 1.0f);           // avg uses raw deg
  }
  sb[threadIdx.x] = c;
  __syncthreads();
  for (int off = 128; off > 0; off >>= 1) {
    if (threadIdx.x < off) sb[threadIdx.x] += sb[threadIdx.x + off];
    __syncthreads();
  }
  if (threadIdx.x == 0) atomicAdd(avgacc, sb[0]);
}

__global__ void finalize_avg_kernel(const double* __restrict__ avgacc,
                                    float* __restrict__ avgf)
{
  *avgf = (float)(*avgacc / (double)N_NODES);
}

// ===================== aggregation: one wave per node =====================
// lane l owns feature l of each segment [x_dst | x_src | ea].
// ea recomputed on the fly from edge_attr (16 attrs broadcast via readlane).

__global__ __launch_bounds__(256) void agg_kernel(
    const float* __restrict__ x, const float* __restrict__ eattr,
    const float* __restrict__ edge_w, const float* __restrict__ edge_b,
    const int* __restrict__ row_ptr, const int2* __restrict__ pairs,
    float* __restrict__ agg)
{
  int lane = threadIdx.x & 63;
  int n = blockIdx.x * 4 + (threadIdx.x >> 6);
  if (n >= N_NODES) return;

  float ew[16];
#pragma unroll
  for (int t = 0; t < 16; t++) ew[t] = edge_w[t * 64 + lane];
  float eb = edge_b[lane];
  float xd = x[n * 64 + lane];

  int s0 = row_ptr[n], s1 = row_ptr[n + 1];
  float sx = 0.f, qx = 0.f, mxx = -3.4e38f, mnx = 3.4e38f;
  float se = 0.f, qe = 0.f, mxe = -3.4e38f, mne = 3.4e38f;

  for (int j = s0; j < s1; j++) {
    int2 p = pairs[j];
    float xs = x[p.x * 64 + lane];
    float av = eattr[p.y * 16 + (lane & 15)];
    unsigned au = __float_as_uint(av);
    float ea = eb;
#pragma unroll
    for (int t = 0; t < 16; t++) {
      float a = __uint_as_float(__builtin_amdgcn_readlane(au, t));
      ea = fmaf(a, ew[t], ea);
    }
    sx += xs; qx = fmaf(xs, xs, qx);
    mxx = fmaxf(mxx, xs); mnx = fminf(mnx, xs);
    se += ea; qe = fmaf(ea, ea, qe);
    mxe = fmaxf(mxe, ea); mne = fminf(mne, ea);
  }

  int deg = s1 - s0;
  float degf = (float)deg;
  float inv = 1.0f / fmaxf(degf, 1.0f);
  bool has = deg > 0;

  // x_dst segment: every edge contributes the same xd
  float m_d  = (degf * xd) * inv;
  float ms_d = (degf * xd * xd) * inv;
  float sd_d = sqrtf(fmaxf(ms_d - m_d * m_d, 0.f) + 1e-5f);
  float mx_d = has ? xd : 0.f;
  float mn_d = mx_d;

  float m_s  = sx * inv, ms_s = qx * inv;
  float sd_s = sqrtf(fmaxf(ms_s - m_s * m_s, 0.f) + 1e-5f);
  float mx_s = has ? mxx : 0.f, mn_s = has ? mnx : 0.f;

  float m_e  = se * inv, ms_e = qe * inv;
  float sd_e = sqrtf(fmaxf(ms_e - m_e * m_e, 0.f) + 1e-5f);
  float mx_e = has ? mxe : 0.f, mn_e = has ? mne : 0.f;

  float* base = agg + (size_t)n * 768;
  base[lane]       = m_d;  base[64 + lane]  = m_s;  base[128 + lane] = m_e;
  base[192 + lane] = mn_d; base[256 + lane] = mn_s; base[320 + lane] = mn_e;
  base[384 + lane] = mx_d; base[448 + lane] = mx_s; base[512 + lane] = mx_e;
  base[576 + lane] = sd_d; base[640 + lane] = sd_s; base[704 + lane] = sd_e;
}

// ===================== GEMM: [N,768] @ [768, 3x64] fused amp/att epilogue ===
// 128x192 tile, BK=32. Thread: 8 rows (tr+16i, bank-conflict-free) x 12 cols
// (4 per segment so epilogue combine needs no cross-thread traffic).

__global__ __launch_bounds__(256, 2) void gemm_kernel(
    const float* __restrict__ agg, const float* __restrict__ W,
    const float* __restrict__ bias, const float* __restrict__ log_deg,
    const float* __restrict__ avg_ptr, float* __restrict__ h)
{
  __shared__ float As[128 * 36];   // 128 rows, stride 36 (pad)
  __shared__ float Bs[32 * 192];   // Bs[k][s*64+j]
  int tid = threadIdx.x;
  int tc = tid & 15;               // col group: j0 = tc*4 in each segment
  int tr = tid >> 4;               // 0..15; rows tr + 16*i
  int n0 = blockIdx.x * 128;

  float acc[3][8][4] = {};

  for (int k0 = 0; k0 < 768; k0 += 32) {
    // A tile: 128x32 = 1024 float4, 4 per thread
#pragma unroll
    for (int q = 0; q < 4; q++) {
      int idx = tid + q * 256;
      int row = idx >> 3, c4 = idx & 7;
      int n = n0 + row;
      float4 v = make_float4(0.f, 0.f, 0.f, 0.f);
      if (n < N_NODES) v = *(const float4*)(agg + (size_t)n * 768 + k0 + c4 * 4);
      *(float4*)(As + row * 36 + c4 * 4) = v;
    }
    // B tile: 3 segs x 32 rows x 16 float4 = 1536 float4, 6 per thread
#pragma unroll
    for (int q = 0; q < 6; q++) {
      int idx = tid + q * 256;
      int s = idx >> 9;
      int r = (idx >> 4) & 31;
      int c4 = idx & 15;
      float4 v = *(const float4*)(W + ((size_t)(s * 768 + k0 + r)) * 64 + c4 * 4);
      *(float4*)(Bs + r * 192 + s * 64 + c4 * 4) = v;
    }
    __syncthreads();

#pragma unroll
    for (int k4 = 0; k4 < 8; k4++) {
      float4 af[8];
#pragma unroll
      for (int i = 0; i < 8; i++)
        af[i] = *(const float4*)(As + (tr + 16 * i) * 36 + k4 * 4);
#pragma unroll
      for (int kk = 0; kk < 4; kk++) {
        const float* bp = Bs + (k4 * 4 + kk) * 192 + tc * 4;
        float4 b0 = *(const float4*)(bp);
        float4 b1 = *(const float4*)(bp + 64);
        float4 b2 = *(const float4*)(bp + 128);
#pragma unroll
        for (int i = 0; i < 8; i++) {
          float a = (&af[i].x)[kk];
          acc[0][i][0] = fmaf(a, b0.x, acc[0][i][0]);
          acc[0][i][1] = fmaf(a, b0.y, acc[0][i][1]);
          acc[0][i][2] = fmaf(a, b0.z, acc[0][i][2]);
          acc[0][i][3] = fmaf(a, b0.w, acc[0][i][3]);
          acc[1][i][0] = fmaf(a, b1.x, acc[1][i][0]);
          acc[1][i][1] = fmaf(a, b1.y, acc[1][i][1]);
          acc[1][i][2] = fmaf(a, b1.z, acc[1][i][2]);
          acc[1][i][3] = fmaf(a, b1.w, acc[1][i][3]);
          acc[2][i][0] = fmaf(a, b2.x, acc[2][i][0]);
          acc[2][i][1] = fmaf(a, b2.y, acc[2][i][1]);
          acc[2][i][2] = fmaf(a, b2.z, acc[2][i][2]);
          acc[2][i][3] = fmaf(a, b2.w, acc[2][i][3]);
        }
      }
    }
    __syncthreads();
  }

  float avg = *avg_ptr;
  float4 bi = *(const float4*)(bias + tc * 4);
#pragma unroll
  for (int i = 0; i < 8; i++) {
    int n = n0 + tr + 16 * i;
    if (n >= N_NODES) continue;
    float ld = log_deg[n];
    float amp = ld / avg;
    float att = avg / ld;
    float4 st;
    st.x = acc[0][i][0] + amp * acc[1][i][0] + att * acc[2][i][0] + bi.x;
    st.y = acc[0][i][1] + amp * acc[1][i][1] + att * acc[2][i][1] + bi.y;
    st.z = acc[0][i][2] + amp * acc[1][i][2] + att * acc[2][i][2] + bi.z;
    st.w = acc[0][i][3] + amp * acc[1][i][3] + att * acc[2][i][3] + bi.w;
    *(float4*)(h + (size_t)n * 64 + tc * 4) = st;
  }
}

// ===================== BatchNorm (training stats) =====================

__global__ __launch_bounds__(256) void bn_stats_kernel(
    const float* __restrict__ h, double* __restrict__ accS, double* __restrict__ accQ)
{
  __shared__ double sb[256], qb[256];
  int tid = threadIdx.x;
  int j = tid & 63, ri = tid >> 6;
  double s = 0.0, q = 0.0;
  for (int n = blockIdx.x * 4 + ri; n < N_NODES; n += 1024) {
    double v = (double)h[(size_t)n * 64 + j];
    s += v; q += v * v;
  }
  sb[tid] = s; qb[tid] = q;
  __syncthreads();
  if (tid < 64) {
    s = sb[tid] + sb[tid + 64] + sb[tid + 128] + sb[tid + 192];
    q = qb[tid] + qb[tid + 64] + qb[tid + 128] + qb[tid + 192];
    atomicAdd(&accS[j], s);
    atomicAdd(&accQ[j], q);
  }
}

__global__ void bn_finalize_kernel(const double* __restrict__ accS,
                                   const double* __restrict__ accQ,
                                   const float* __restrict__ g,
                                   float* __restrict__ muf, float* __restrict__ scf)
{
  int j = threadIdx.x;  // 64 threads
  double mu = accS[j] / (double)N_NODES;
  double var = accQ[j] / (double)N_NODES - mu * mu;
  double rstd = 1.0 / sqrt(var + 1e-5);
  muf[j] = (float)mu;
  scf[j] = (float)(rstd * (double)g[j]);
}

__global__ __launch_bounds__(256) void apply_kernel(
    const float* __restrict__ h, const float* __restrict__ muf,
    const float* __restrict__ scf, const float* __restrict__ bnb,
    float* __restrict__ x)
{
  int i4 = blockIdx.x * 256 + threadIdx.x;   // float4 index, exact grid
  const float4* h4 = (const float4*)h;
  float4* x4 = (float4*)x;
  int c4 = i4 & 15;
  float4 hv = h4[i4], xv = x4[i4];
  float4 mu = ((const float4*)muf)[c4];
  float4 sc = ((const float4*)scf)[c4];
  float4 bb = ((const float4*)bnb)[c4];
  float4 r;
  r.x = fmaxf((hv.x - mu.x) * sc.x + bb.x, 0.f) + xv.x;
  r.y = fmaxf((hv.y - mu.y) * sc.y + bb.y, 0.f) + xv.y;
  r.z = fmaxf((hv.z - mu.z) * sc.z + bb.z, 0.f) + xv.z;
  r.w = fmaxf((hv.w - mu.w) * sc.w + bb.w, 0.f) + xv.w;
  x4[i4] = r;
}

// ===================== pooling + head =====================

__global__ __launch_bounds__(256) void pool_kernel(
    const float* __restrict__ x, const int* __restrict__ batch,
    float* __restrict__ gsum)
{
  int tid = threadIdx.x;
  int j = tid & 63, ri = tid >> 6;
  float acc = 0.f; int cur = -1;
  for (int k = 0; k < 16; k++) {
    int n = blockIdx.x * 64 + k * 4 + ri;
    if (n < N_NODES) {
      int b = batch[n];
      if (b != cur) {
        if (cur >= 0) atomicAdd(&gsum[cur * 64 + j], acc);
        cur = b; acc = 0.f;
      }
      acc += x[(size_t)n * 64 + j];
    }
  }
  if (cur >= 0) atomicAdd(&gsum[cur * 64 + j], acc);
}

__global__ void gcnt_kernel(const int* __restrict__ batch, int* __restrict__ gcnt)
{
  int n = blockIdx.x * 256 + threadIdx.x;
  if (n < N_NODES) atomicAdd(&gcnt[batch[n]], 1);
}

__global__ void fc_kernel(const float* __restrict__ gsum, const int* __restrict__ gcnt,
                          const float* __restrict__ w1, const float* __restrict__ b1,
                          const float* __restrict__ w2, const float* __restrict__ b2,
                          const float* __restrict__ w3, const float* __restrict__ b3,
                          float* __restrict__ out)
{
  int g = threadIdx.x;  // 64 threads, one per graph
  float cnt = fmaxf((float)gcnt[g], 1.0f);
  float gv[64];
#pragma unroll
  for (int j = 0; j < 64; j++) gv[j] = gsum[g * 64 + j] / cnt;
  float a1[32];
#pragma unroll
  for (int o = 0; o < 32; o++) {
    float s = b1[o];
#pragma unroll
    for (int j = 0; j < 64; j++) s = fmaf(gv[j], w1[j * 32 + o], s);
    a1[o] = fmaxf(s, 0.f);
  }
  float a2[16];
#pragma unroll
  for (int o = 0; o < 16; o++) {
    float s = b2[o];
#pragma unroll
    for (int j = 0; j < 32; j++) s = fmaf(a1[j], w2[j * 16 + o], s);
    a2[o] = fmaxf(s, 0.f);
  }
#pragma unroll
  for (int o = 0; o < 10; o++) {
    float s = b3[o];
#pragma unroll
    for (int j = 0; j < 16; j++) s = fmaf(a2[j], w3[j * 10 + o], s);
    out[g * 10 + o] = s;
  }
}

// ===================== launch =====================

extern "C" void kernel_launch(void* const* d_in, const int* in_sizes, int n_in,
                              void* d_out, int out_size, void* d_ws, size_t ws_size,
                              hipStream_t stream)
{
  (void)in_sizes; (void)n_in; (void)out_size; (void)ws_size;
  const float* xin    = (const float*)d_in[0];
  const int*   ei     = (const int*)d_in[1];
  const int*   batch  = (const int*)d_in[2];
  const float* eattr  = (const float*)d_in[3];
  const float* node_w = (const float*)d_in[4];
  const float* node_b = (const float*)d_in[5];
  const float* edge_w = (const float*)d_in[6];
  const float* edge_b = (const float*)d_in[7];
  const float* conv_w = (const float*)d_in[8];
  const float* conv_b = (const float*)d_in[9];
  const float* bn_g   = (const float*)d_in[10];
  const float* bn_b   = (const float*)d_in[11];
  const float* fc1_w  = (const float*)d_in[12];
  const float* fc1_b  = (const float*)d_in[13];
  const float* fc2_w  = (const float*)d_in[14];
  const float* fc2_b  = (const float*)d_in[15];
  const float* fc3_w  = (const float*)d_in[16];
  const float* fc3_b  = (const float*)d_in[17];
  float* out = (float*)d_out;
  const int* srcp = ei;
  const int* dstp = ei + N_EDGES;

  char* p = (char*)d_ws;
  auto alloc = [&](size_t b) { char* r = p; p += (b + 255) & ~(size_t)255; return (void*)r; };
  float*  x       = (float*)alloc((size_t)N_NODES * 64 * 4);
  float*  h       = (float*)alloc((size_t)N_NODES * 64 * 4);
  float*  agg     = (float*)alloc((size_t)N_NODES * 768 * 4);
  int2*   pairs   = (int2*)alloc((size_t)N_EDGES * 8);
  int*    row_ptr = (int*)alloc((N_NODES + 1) * 4);
  int*    cursor  = (int*)alloc((size_t)N_NODES * 4);
  int*    cnt     = (int*)alloc((size_t)N_NODES * 4);
  float*  log_deg = (float*)alloc((size_t)N_NODES * 4);
  int*    bsum    = (int*)alloc(256 * 4);
  int*    boff    = (int*)alloc(256 * 4);
  double* avgacc  = (double*)alloc(256);
  float*  avgf    = (float*)alloc(256);
  double* bnacc   = (double*)alloc(128 * 8);
  float*  muf     = (float*)alloc(256);
  float*  scf     = (float*)alloc(256);
  float*  gsum    = (float*)alloc((size_t)NGRAPH * 64 * 4);
  int*    gcnt    = (int*)alloc((size_t)NGRAPH * 4);

  hipMemsetAsync(cnt, 0, (size_t)N_NODES * 4, stream);
  hipMemsetAsync(avgacc, 0, 8, stream);
  hipMemsetAsync(gsum, 0, (size_t)NGRAPH * 64 * 4, stream);
  hipMemsetAsync(gcnt, 0, (size_t)NGRAPH * 4, stream);

  node_enc_kernel<<<12500, 256, 0, stream>>>(xin, node_w, node_b, x);
  count_kernel<<<3125, 256, 0, stream>>>(dstp, cnt);
  scan_a_kernel<<<196, 256, 0, stream>>>(cnt, bsum);
  scan_b_kernel<<<1, 256, 0, stream>>>(bsum, boff);
  scan_c_kernel<<<196, 256, 0, stream>>>(cnt, boff, row_ptr);
  hipMemcpyAsync(cursor, row_ptr, (size_t)N_NODES * 4, hipMemcpyDeviceToDevice, stream);
  fill_kernel<<<3125, 256, 0, stream>>>(srcp, dstp, cursor, pairs);
  deg_log_kernel<<<196, 256, 0, stream>>>(cnt, log_deg, avgacc);
  finalize_avg_kernel<<<1, 1, 0, stream>>>(avgacc, avgf);

  for (int l = 0; l < 3; l++) {
    agg_kernel<<<12500, 256, 0, stream>>>(x, eattr, edge_w, edge_b, row_ptr, pairs, agg);
    gemm_kernel<<<391, 256, 0, stream>>>(agg, conv_w + (size_t)l * 2304 * 64,
                                         conv_b + l * 64, log_deg, avgf, h);
    hipMemsetAsync(bnacc, 0, 128 * 8, stream);
    bn_stats_kernel<<<256, 256, 0, stream>>>(h, bnacc, bnacc + 64);
    bn_finalize_kernel<<<1, 64, 0, stream>>>(bnacc, bnacc + 64, bn_g + l * 64, muf, scf);
    apply_kernel<<<3125, 256, 0, stream>>>(h, muf, scf, bn_b + l * 64, x);
  }

  pool_kernel<<<782, 256, 0, stream>>>(x, batch, gsum);
  gcnt_kernel<<<196, 256, 0, stream>>>(batch, gcnt);
  fc_kernel<<<1, 64, 0, stream>>>(gsum, gcnt, fc1_w, fc1_b, fc2_w, fc2_b,
                                  fc3_w, fc3_b, out);
}

// Round 2
// 1303.003 us; speedup vs baseline: 1.1858x; 1.1858x over previous
//
#include <hip/hip_runtime.h>
#include <math.h>

#define N_NODES 50000
#define N_EDGES 800000
#define NGRAPH  64
#define KEFF    576   // compressed agg width: [xd_has | m_s m_e | mn_s mn_e | mx_s mx_e | sd_s sd_e]

// ===================== setup kernels =====================

__global__ __launch_bounds__(256) void node_enc_kernel(
    const float* __restrict__ xin, const float* __restrict__ nw,
    const float* __restrict__ nb, float* __restrict__ x)
{
  __shared__ float xs[256];
  int tid = threadIdx.x;
  int base = blockIdx.x * 256;          // 4 nodes per block
  xs[tid] = xin[base + tid];
  __syncthreads();
  int r = tid >> 6, j = tid & 63;
  float acc = nb[j];
#pragma unroll
  for (int t = 0; t < 64; t++) acc = fmaf(xs[r * 64 + t], nw[t * 64 + j], acc);
  x[base + tid] = acc;
}

__global__ void count_kernel(const int* __restrict__ dst, int* __restrict__ cnt)
{
  int e = blockIdx.x * 256 + threadIdx.x;   // grid exactly covers E
  atomicAdd(&cnt[dst[e]], 1);
}

__global__ __launch_bounds__(256) void scan_a_kernel(
    const int* __restrict__ cnt, int* __restrict__ bsum)
{
  __shared__ int s[256];
  int i = blockIdx.x * 256 + threadIdx.x;
  s[threadIdx.x] = (i < N_NODES) ? cnt[i] : 0;
  __syncthreads();
  for (int off = 128; off > 0; off >>= 1) {
    if (threadIdx.x < off) s[threadIdx.x] += s[threadIdx.x + off];
    __syncthreads();
  }
  if (threadIdx.x == 0) bsum[blockIdx.x] = s[0];
}

__global__ __launch_bounds__(256) void scan_b_kernel(
    const int* __restrict__ bsum, int* __restrict__ boff)
{
  __shared__ int s[256];
  int tid = threadIdx.x;
  int v = (tid < 196) ? bsum[tid] : 0;
  s[tid] = v;
  __syncthreads();
  for (int off = 1; off < 256; off <<= 1) {
    int t = (tid >= off) ? s[tid - off] : 0;
    __syncthreads();
    s[tid] += t;
    __syncthreads();
  }
  boff[tid] = s[tid] - v;   // exclusive prefix of block sums
}

__global__ __launch_bounds__(256) void scan_c_kernel(
    const int* __restrict__ cnt, const int* __restrict__ boff,
    int* __restrict__ row_ptr)
{
  __shared__ int s[256];
  int tid = threadIdx.x;
  int i = blockIdx.x * 256 + tid;
  int v = (i < N_NODES) ? cnt[i] : 0;
  s[tid] = v;
  __syncthreads();
  for (int off = 1; off < 256; off <<= 1) {
    int t = (tid >= off) ? s[tid - off] : 0;
    __syncthreads();
    s[tid] += t;
    __syncthreads();
  }
  int incl = s[tid];
  int base = boff[blockIdx.x];
  if (i < N_NODES) row_ptr[i] = base + incl - v;
  if (i == N_NODES - 1) row_ptr[N_NODES] = base + incl;
}

__global__ void fill_kernel(const int* __restrict__ src, const int* __restrict__ dst,
                            int* __restrict__ cursor, int2* __restrict__ pairs)
{
  int e = blockIdx.x * 256 + threadIdx.x;
  int d = dst[e];
  int pos = atomicAdd(&cursor[d], 1);
  pairs[pos] = make_int2(src[e], e);
}

__global__ __launch_bounds__(256) void deg_log_kernel(
    const int* __restrict__ cnt, float* __restrict__ log_deg,
    double* __restrict__ avgacc)
{
  __shared__ double sb[256];
  int i = blockIdx.x * 256 + threadIdx.x;
  double c = 0.0;
  if (i < N_NODES) {
    int d = cnt[i];
    int dc = d > 0 ? d : 1;
    log_deg[i] = logf((float)dc + 1.0f);         // log(degc + 1)
    c = (double)logf((float)d + 1.0f);           // avg uses raw deg
  }
  sb[threadIdx.x] = c;
  __syncthreads();
  for (int off = 128; off > 0; off >>= 1) {
    if (threadIdx.x < off) sb[threadIdx.x] += sb[threadIdx.x + off];
    __syncthreads();
  }
  if (threadIdx.x == 0) atomicAdd(avgacc, sb[0]);
}

__global__ void finalize_avg_kernel(const double* __restrict__ avgacc,
                                    float* __restrict__ avgf)
{
  *avgf = (float)(*avgacc / (double)N_NODES);
}

// graph node counts from sorted batch via binary search (replaces 50k same-line atomics)
__global__ void gbound_kernel(const int* __restrict__ batch, int* __restrict__ gcnt)
{
  __shared__ int sb[65];
  int g = threadIdx.x;  // 64 threads
  int lo = 0, hi = N_NODES;
  while (lo < hi) { int mid = (lo + hi) >> 1; if (batch[mid] < g) lo = mid + 1; else hi = mid; }
  sb[g] = lo;
  if (g == 0) sb[64] = N_NODES;
  __syncthreads();
  gcnt[g] = sb[g + 1] - sb[g];
}

// ===================== weight compression =====================
// agg columns 768 -> 576: mean_d == mn_d == mx_d == xd*(deg>0)  (fold 3 weight segs),
// sd_d == sqrt(1e-5) for every node (fold into per-column bias).
// weff layout [l][s][k=576][j=64]; srcseg for k>=64: {1,2,4,5,7,8,10,11}

__global__ __launch_bounds__(256) void wprep_kernel(
    const float* __restrict__ conv_w, float* __restrict__ weff)
{
  int idx = blockIdx.x * 256 + threadIdx.x;   // 3*3*576*64 = 331776 = 1296*256
  int j = idx & 63;
  int k = (idx >> 6) % 576;
  int s = ((idx >> 6) / 576) % 3;
  int l = idx / (64 * 576 * 3);
  const float* CW = conv_w + (size_t)l * 2304 * 64;
  float v;
  if (k < 64) {
    int base = s * 768 + k;
    v = CW[base * 64 + j] + CW[(base + 192) * 64 + j] + CW[(base + 384) * 64 + j];
  } else {
    const int srcseg[8] = {1, 2, 4, 5, 7, 8, 10, 11};
    int q = (k >> 6) - 1;
    int t = k & 63;
    v = CW[(s * 768 + srcseg[q] * 64 + t) * 64 + j];
  }
  weff[idx] = v;
}

__global__ void bprep_kernel(const float* __restrict__ conv_w, float* __restrict__ beff)
{
  int l = blockIdx.x;                 // 3 blocks x 192 threads
  int s = threadIdx.x >> 6, j = threadIdx.x & 63;
  const float* CW = conv_w + (size_t)l * 2304 * 64 + (size_t)(s * 768 + 576) * 64;
  float sum = 0.f;
#pragma unroll
  for (int t = 0; t < 64; t++) sum += CW[t * 64 + j];
  beff[(l * 3 + s) * 64 + j] = sum * 0.0031622776601683794f;   // sqrt(1e-5)
}

// ===================== aggregation: one wave per node =====================

__global__ __launch_bounds__(256) void agg_kernel(
    const float* __restrict__ x, const float* __restrict__ eattr,
    const float* __restrict__ edge_w, const float* __restrict__ edge_b,
    const int* __restrict__ row_ptr, const int2* __restrict__ pairs,
    float* __restrict__ agg)
{
  int lane = threadIdx.x & 63;
  int n = blockIdx.x * 4 + (threadIdx.x >> 6);
  if (n >= N_NODES) return;

  float ew[16];
#pragma unroll
  for (int t = 0; t < 16; t++) ew[t] = edge_w[t * 64 + lane];
  float eb = edge_b[lane];
  float xd = x[n * 64 + lane];

  int s0 = row_ptr[n], s1 = row_ptr[n + 1];
  float sx = 0.f, qx = 0.f, mxx = -3.4e38f, mnx = 3.4e38f;
  float se = 0.f, qe = 0.f, mxe = -3.4e38f, mne = 3.4e38f;

  for (int j = s0; j < s1; j++) {
    int2 p = pairs[j];
    float xs = x[p.x * 64 + lane];
    float av = eattr[p.y * 16 + (lane & 15)];
    unsigned au = __float_as_uint(av);
    float ea = eb;
#pragma unroll
    for (int t = 0; t < 16; t++) {
      float a = __uint_as_float(__builtin_amdgcn_readlane(au, t));
      ea = fmaf(a, ew[t], ea);
    }
    sx += xs; qx = fmaf(xs, xs, qx);
    mxx = fmaxf(mxx, xs); mnx = fminf(mnx, xs);
    se += ea; qe = fmaf(ea, ea, qe);
    mxe = fmaxf(mxe, ea); mne = fminf(mne, ea);
  }

  int deg = s1 - s0;
  float degf = (float)deg;
  float inv = 1.0f / fmaxf(degf, 1.0f);
  bool has = deg > 0;

  float m_s  = sx * inv, ms_s = qx * inv;
  float sd_s = sqrtf(fmaxf(ms_s - m_s * m_s, 0.f) + 1e-5f);
  float mx_s = has ? mxx : 0.f, mn_s = has ? mnx : 0.f;

  float m_e  = se * inv, ms_e = qe * inv;
  float sd_e = sqrtf(fmaxf(ms_e - m_e * m_e, 0.f) + 1e-5f);
  float mx_e = has ? mxe : 0.f, mn_e = has ? mne : 0.f;

  float* base = agg + (size_t)n * KEFF;
  base[lane]       = has ? xd : 0.f;
  base[64 + lane]  = m_s;  base[128 + lane] = m_e;
  base[192 + lane] = mn_s; base[256 + lane] = mn_e;
  base[320 + lane] = mx_s; base[384 + lane] = mx_e;
  base[448 + lane] = sd_s; base[512 + lane] = sd_e;
}

// ===================== GEMM: [N,576] @ [576, 3x64], fused epilogue =========
// 128 threads, 64x192 tile, grid 782 (~3 blocks/CU). A read straight from
// global (16-way redundancy absorbed by L1; 1KB distinct per k4 per block),
// LDS holds only B (24.5KB) -> VALU-bound instead of LDS-pipe-bound.

__global__ __launch_bounds__(128, 2) void gemm_kernel(
    const float* __restrict__ agg, const float* __restrict__ W,
    const float* __restrict__ beff, const float* __restrict__ bias,
    const float* __restrict__ log_deg, const float* __restrict__ avg_ptr,
    float* __restrict__ h)
{
  __shared__ float Bs[32 * 192];
  int tid = threadIdx.x;
  int tc = tid & 15;               // col group: j0 = tc*4 in each segment
  int tr = tid >> 4;               // 0..7; rows tr + 8*i
  int n0 = blockIdx.x * 64;

  const float* ap[8];
#pragma unroll
  for (int i = 0; i < 8; i++) {
    int n = n0 + tr + 8 * i;
    ap[i] = agg + (size_t)(n < N_NODES ? n : 0) * KEFF;
  }

  float acc[3][8][4] = {};

  for (int k0 = 0; k0 < KEFF; k0 += 32) {
    // B tile: 3 segs x 32 rows x 16 float4 = 1536 float4, 12 per thread
#pragma unroll
    for (int q = 0; q < 12; q++) {
      int idx = tid + q * 128;
      int s = idx >> 9;
      int r = (idx >> 4) & 31;
      int c4 = idx & 15;
      float4 v = *(const float4*)(W + ((size_t)(s * KEFF + k0 + r)) * 64 + c4 * 4);
      *(float4*)(Bs + r * 192 + s * 64 + c4 * 4) = v;
    }
    __syncthreads();

#pragma unroll 2
    for (int k4 = 0; k4 < 8; k4++) {
      float4 af[8];
#pragma unroll
      for (int i = 0; i < 8; i++)
        af[i] = *(const float4*)(ap[i] + k0 + k4 * 4);
#pragma unroll
      for (int kk = 0; kk < 4; kk++) {
        const float* bp = Bs + (k4 * 4 + kk) * 192 + tc * 4;
        float4 b0 = *(const float4*)(bp);
        float4 b1 = *(const float4*)(bp + 64);
        float4 b2 = *(const float4*)(bp + 128);
#pragma unroll
        for (int i = 0; i < 8; i++) {
          float a = (&af[i].x)[kk];
          acc[0][i][0] = fmaf(a, b0.x, acc[0][i][0]);
          acc[0][i][1] = fmaf(a, b0.y, acc[0][i][1]);
          acc[0][i][2] = fmaf(a, b0.z, acc[0][i][2]);
          acc[0][i][3] = fmaf(a, b0.w, acc[0][i][3]);
          acc[1][i][0] = fmaf(a, b1.x, acc[1][i][0]);
          acc[1][i][1] = fmaf(a, b1.y, acc[1][i][1]);
          acc[1][i][2] = fmaf(a, b1.z, acc[1][i][2]);
          acc[1][i][3] = fmaf(a, b1.w, acc[1][i][3]);
          acc[2][i][0] = fmaf(a, b2.x, acc[2][i][0]);
          acc[2][i][1] = fmaf(a, b2.y, acc[2][i][1]);
          acc[2][i][2] = fmaf(a, b2.z, acc[2][i][2]);
          acc[2][i][3] = fmaf(a, b2.w, acc[2][i][3]);
        }
      }
    }
    __syncthreads();
  }

  float avg = *avg_ptr;
  float4 bi  = *(const float4*)(bias + tc * 4);
  float4 be0 = *(const float4*)(beff + tc * 4);
  float4 be1 = *(const float4*)(beff + 64 + tc * 4);
  float4 be2 = *(const float4*)(beff + 128 + tc * 4);
#pragma unroll
  for (int i = 0; i < 8; i++) {
    int n = n0 + tr + 8 * i;
    if (n >= N_NODES) continue;
    float ld = log_deg[n];
    float amp = ld / avg;
    float att = avg / ld;
    float4 st;
    st.x = (acc[0][i][0] + be0.x) + amp * (acc[1][i][0] + be1.x) + att * (acc[2][i][0] + be2.x) + bi.x;
    st.y = (acc[0][i][1] + be0.y) + amp * (acc[1][i][1] + be1.y) + att * (acc[2][i][1] + be2.y) + bi.y;
    st.z = (acc[0][i][2] + be0.z) + amp * (acc[1][i][2] + be1.z) + att * (acc[2][i][2] + be2.z) + bi.z;
    st.w = (acc[0][i][3] + be0.w) + amp * (acc[1][i][3] + be1.w) + att * (acc[2][i][3] + be2.w) + bi.w;
    *(float4*)(h + (size_t)n * 64 + tc * 4) = st;
  }
}

// ===================== BatchNorm (training stats) =====================

__global__ __launch_bounds__(256) void bn_stats_kernel(
    const float* __restrict__ h, double* __restrict__ accS, double* __restrict__ accQ)
{
  __shared__ double sb[256], qb[256];
  int tid = threadIdx.x;
  int j = tid & 63, ri = tid >> 6;
  double s = 0.0, q = 0.0;
  for (int n = blockIdx.x * 4 + ri; n < N_NODES; n += 1024) {
    double v = (double)h[(size_t)n * 64 + j];
    s += v; q += v * v;
  }
  sb[tid] = s; qb[tid] = q;
  __syncthreads();
  if (tid < 64) {
    s = sb[tid] + sb[tid + 64] + sb[tid + 128] + sb[tid + 192];
    q = qb[tid] + qb[tid + 64] + qb[tid + 128] + qb[tid + 192];
    atomicAdd(&accS[j], s);
    atomicAdd(&accQ[j], q);
  }
}

__global__ void bn_finalize_kernel(const double* __restrict__ accS,
                                   const double* __restrict__ accQ,
                                   const float* __restrict__ g,
                                   float* __restrict__ muf, float* __restrict__ scf)
{
  int j = threadIdx.x;  // 64 threads
  double mu = accS[j] / (double)N_NODES;
  double var = accQ[j] / (double)N_NODES - mu * mu;
  double rstd = 1.0 / sqrt(var + 1e-5);
  muf[j] = (float)mu;
  scf[j] = (float)(rstd * (double)g[j]);
}

__global__ __launch_bounds__(256) void apply_kernel(
    const float* __restrict__ h, const float* __restrict__ muf,
    const float* __restrict__ scf, const float* __restrict__ bnb,
    float* __restrict__ x)
{
  int i4 = blockIdx.x * 256 + threadIdx.x;   // float4 index, exact grid
  const float4* h4 = (const float4*)h;
  float4* x4 = (float4*)x;
  int c4 = i4 & 15;
  float4 hv = h4[i4], xv = x4[i4];
  float4 mu = ((const float4*)muf)[c4];
  float4 sc = ((const float4*)scf)[c4];
  float4 bb = ((const float4*)bnb)[c4];
  float4 r;
  r.x = fmaxf((hv.x - mu.x) * sc.x + bb.x, 0.f) + xv.x;
  r.y = fmaxf((hv.y - mu.y) * sc.y + bb.y, 0.f) + xv.y;
  r.z = fmaxf((hv.z - mu.z) * sc.z + bb.z, 0.f) + xv.z;
  r.w = fmaxf((hv.w - mu.w) * sc.w + bb.w, 0.f) + xv.w;
  x4[i4] = r;
}

// ===================== pooling + head =====================

__global__ __launch_bounds__(256) void pool_kernel(
    const float* __restrict__ x, const int* __restrict__ batch,
    float* __restrict__ gsum)
{
  int tid = threadIdx.x;
  int j = tid & 63, ri = tid >> 6;
  float acc = 0.f; int cur = -1;
  for (int k = 0; k < 16; k++) {
    int n = blockIdx.x * 64 + k * 4 + ri;
    if (n < N_NODES) {
      int b = batch[n];
      if (b != cur) {
        if (cur >= 0) atomicAdd(&gsum[cur * 64 + j], acc);
        cur = b; acc = 0.f;
      }
      acc += x[(size_t)n * 64 + j];
    }
  }
  if (cur >= 0) atomicAdd(&gsum[cur * 64 + j], acc);
}

__global__ void fc_kernel(const float* __restrict__ gsum, const int* __restrict__ gcnt,
                          const float* __restrict__ w1, const float* __restrict__ b1,
                          const float* __restrict__ w2, const float* __restrict__ b2,
                          const float* __restrict__ w3, const float* __restrict__ b3,
                          float* __restrict__ out)
{
  int g = threadIdx.x;  // 64 threads, one per graph
  float cnt = fmaxf((float)gcnt[g], 1.0f);
  float gv[64];
#pragma unroll
  for (int j = 0; j < 64; j++) gv[j] = gsum[g * 64 + j] / cnt;
  float a1[32];
#pragma unroll
  for (int o = 0; o < 32; o++) {
    float s = b1[o];
#pragma unroll
    for (int j = 0; j < 64; j++) s = fmaf(gv[j], w1[j * 32 + o], s);
    a1[o] = fmaxf(s, 0.f);
  }
  float a2[16];
#pragma unroll
  for (int o = 0; o < 16; o++) {
    float s = b2[o];
#pragma unroll
    for (int j = 0; j < 32; j++) s = fmaf(a1[j], w2[j * 16 + o], s);
    a2[o] = fmaxf(s, 0.f);
  }
#pragma unroll
  for (int o = 0; o < 10; o++) {
    float s = b3[o];
#pragma unroll
    for (int j = 0; j < 16; j++) s = fmaf(a2[j], w3[j * 10 + o], s);
    out[g * 10 + o] = s;
  }
}

// ===================== launch =====================

extern "C" void kernel_launch(void* const* d_in, const int* in_sizes, int n_in,
                              void* d_out, int out_size, void* d_ws, size_t ws_size,
                              hipStream_t stream)
{
  (void)in_sizes; (void)n_in; (void)out_size; (void)ws_size;
  const float* xin    = (const float*)d_in[0];
  const int*   ei     = (const int*)d_in[1];
  const int*   batch  = (const int*)d_in[2];
  const float* eattr  = (const float*)d_in[3];
  const float* node_w = (const float*)d_in[4];
  const float* node_b = (const float*)d_in[5];
  const float* edge_w = (const float*)d_in[6];
  const float* edge_b = (const float*)d_in[7];
  const float* conv_w = (const float*)d_in[8];
  const float* conv_b = (const float*)d_in[9];
  const float* bn_g   = (const float*)d_in[10];
  const float* bn_b   = (const float*)d_in[11];
  const float* fc1_w  = (const float*)d_in[12];
  const float* fc1_b  = (const float*)d_in[13];
  const float* fc2_w  = (const float*)d_in[14];
  const float* fc2_b  = (const float*)d_in[15];
  const float* fc3_w  = (const float*)d_in[16];
  const float* fc3_b  = (const float*)d_in[17];
  float* out = (float*)d_out;
  const int* srcp = ei;
  const int* dstp = ei + N_EDGES;

  char* p = (char*)d_ws;
  auto alloc = [&](size_t b) { char* r = p; p += (b + 255) & ~(size_t)255; return (void*)r; };
  float*  x       = (float*)alloc((size_t)N_NODES * 64 * 4);
  float*  h       = (float*)alloc((size_t)N_NODES * 64 * 4);
  float*  agg     = (float*)alloc((size_t)N_NODES * KEFF * 4);
  int2*   pairs   = (int2*)alloc((size_t)N_EDGES * 8);
  float*  weff    = (float*)alloc((size_t)3 * 3 * KEFF * 64 * 4);
  float*  beff    = (float*)alloc((size_t)3 * 3 * 64 * 4);
  int*    row_ptr = (int*)alloc((N_NODES + 1) * 4);
  int*    cursor  = (int*)alloc((size_t)N_NODES * 4);
  int*    cnt     = (int*)alloc((size_t)N_NODES * 4);
  float*  log_deg = (float*)alloc((size_t)N_NODES * 4);
  int*    bsum    = (int*)alloc(256 * 4);
  int*    boff    = (int*)alloc(256 * 4);
  double* avgacc  = (double*)alloc(256);
  float*  avgf    = (float*)alloc(256);
  double* bnacc   = (double*)alloc(128 * 8);
  float*  muf     = (float*)alloc(256);
  float*  scf     = (float*)alloc(256);
  float*  gsum    = (float*)alloc((size_t)NGRAPH * 64 * 4);
  int*    gcnt    = (int*)alloc((size_t)NGRAPH * 4);

  hipMemsetAsync(cnt, 0, (size_t)N_NODES * 4, stream);
  hipMemsetAsync(avgacc, 0, 8, stream);
  hipMemsetAsync(gsum, 0, (size_t)NGRAPH * 64 * 4, stream);

  node_enc_kernel<<<12500, 256, 0, stream>>>(xin, node_w, node_b, x);
  count_kernel<<<3125, 256, 0, stream>>>(dstp, cnt);
  scan_a_kernel<<<196, 256, 0, stream>>>(cnt, bsum);
  scan_b_kernel<<<1, 256, 0, stream>>>(bsum, boff);
  scan_c_kernel<<<196, 256, 0, stream>>>(cnt, boff, row_ptr);
  hipMemcpyAsync(cursor, row_ptr, (size_t)N_NODES * 4, hipMemcpyDeviceToDevice, stream);
  fill_kernel<<<3125, 256, 0, stream>>>(srcp, dstp, cursor, pairs);
  deg_log_kernel<<<196, 256, 0, stream>>>(cnt, log_deg, avgacc);
  finalize_avg_kernel<<<1, 1, 0, stream>>>(avgacc, avgf);
  gbound_kernel<<<1, 64, 0, stream>>>(batch, gcnt);
  wprep_kernel<<<1296, 256, 0, stream>>>(conv_w, weff);
  bprep_kernel<<<3, 192, 0, stream>>>(conv_w, beff);

  for (int l = 0; l < 3; l++) {
    agg_kernel<<<12500, 256, 0, stream>>>(x, eattr, edge_w, edge_b, row_ptr, pairs, agg);
    gemm_kernel<<<782, 128, 0, stream>>>(agg, weff + (size_t)l * 3 * KEFF * 64,
                                         beff + (size_t)l * 192, conv_b + l * 64,
                                         log_deg, avgf, h);
    hipMemsetAsync(bnacc, 0, 128 * 8, stream);
    bn_stats_kernel<<<256, 256, 0, stream>>>(h, bnacc, bnacc + 64);
    bn_finalize_kernel<<<1, 64, 0, stream>>>(bnacc, bnacc + 64, bn_g + l * 64, muf, scf);
    apply_kernel<<<3125, 256, 0, stream>>>(h, muf, scf, bn_b + l * 64, x);
  }

  pool_kernel<<<782, 256, 0, stream>>>(x, batch, gsum);
  gbound_kernel<<<1, 64, 0, stream>>>(batch, gcnt);
  fc_kernel<<<1, 64, 0, stream>>>(gsum, gcnt, fc1_w, fc1_b, fc2_w, fc2_b,
                                  fc3_w, fc3_b, out);
}

// Round 3
// 885.814 us; speedup vs baseline: 1.7442x; 1.4710x over previous
//
#include <hip/hip_runtime.h>
#include <math.h>

#define N_NODES 50000
#define N_EDGES 800000
#define NGRAPH  64
#define KEFF    576   // compressed agg width (768->576 via x_dst folding)

typedef short bf16x8 __attribute__((ext_vector_type(8)));
typedef float f32x4  __attribute__((ext_vector_type(4)));

__device__ inline unsigned short f2bf_rne(float f) {
  unsigned u = __float_as_uint(f);
  unsigned r = u + 0x7FFFu + ((u >> 16) & 1u);
  return (unsigned short)(r >> 16);
}
__device__ inline float bf2f(unsigned short h) {
  return __uint_as_float(((unsigned)h) << 16);
}

// ===================== setup kernels =====================

__global__ __launch_bounds__(256) void node_enc_kernel(
    const float* __restrict__ xin, const float* __restrict__ nw,
    const float* __restrict__ nb, float* __restrict__ x)
{
  __shared__ float xs[256];
  int tid = threadIdx.x;
  int base = blockIdx.x * 256;          // 4 nodes per block
  xs[tid] = xin[base + tid];
  __syncthreads();
  int r = tid >> 6, j = tid & 63;
  float acc = nb[j];
#pragma unroll
  for (int t = 0; t < 64; t++) acc = fmaf(xs[r * 64 + t], nw[t * 64 + j], acc);
  x[base + tid] = acc;
}

__global__ void count_kernel(const int* __restrict__ dst, int* __restrict__ cnt)
{
  int e = blockIdx.x * 256 + threadIdx.x;   // grid exactly covers E
  atomicAdd(&cnt[dst[e]], 1);
}

__global__ __launch_bounds__(256) void scan_a_kernel(
    const int* __restrict__ cnt, int* __restrict__ bsum)
{
  __shared__ int s[256];
  int i = blockIdx.x * 256 + threadIdx.x;
  s[threadIdx.x] = (i < N_NODES) ? cnt[i] : 0;
  __syncthreads();
  for (int off = 128; off > 0; off >>= 1) {
    if (threadIdx.x < off) s[threadIdx.x] += s[threadIdx.x + off];
    __syncthreads();
  }
  if (threadIdx.x == 0) bsum[blockIdx.x] = s[0];
}

__global__ __launch_bounds__(256) void scan_b_kernel(
    const int* __restrict__ bsum, int* __restrict__ boff)
{
  __shared__ int s[256];
  int tid = threadIdx.x;
  int v = (tid < 196) ? bsum[tid] : 0;
  s[tid] = v;
  __syncthreads();
  for (int off = 1; off < 256; off <<= 1) {
    int t = (tid >= off) ? s[tid - off] : 0;
    __syncthreads();
    s[tid] += t;
    __syncthreads();
  }
  boff[tid] = s[tid] - v;   // exclusive prefix of block sums
}

__global__ __launch_bounds__(256) void scan_c_kernel(
    const int* __restrict__ cnt, const int* __restrict__ boff,
    int* __restrict__ row_ptr)
{
  __shared__ int s[256];
  int tid = threadIdx.x;
  int i = blockIdx.x * 256 + tid;
  int v = (i < N_NODES) ? cnt[i] : 0;
  s[tid] = v;
  __syncthreads();
  for (int off = 1; off < 256; off <<= 1) {
    int t = (tid >= off) ? s[tid - off] : 0;
    __syncthreads();
    s[tid] += t;
    __syncthreads();
  }
  int incl = s[tid];
  int base = boff[blockIdx.x];
  if (i < N_NODES) row_ptr[i] = base + incl - v;
  if (i == N_NODES - 1) row_ptr[N_NODES] = base + incl;
}

__global__ void fill_kernel(const int* __restrict__ src, const int* __restrict__ dst,
                            int* __restrict__ cursor, int2* __restrict__ pairs)
{
  int e = blockIdx.x * 256 + threadIdx.x;
  int d = dst[e];
  int pos = atomicAdd(&cursor[d], 1);
  pairs[pos] = make_int2(src[e], e);
}

__global__ __launch_bounds__(256) void deg_log_kernel(
    const int* __restrict__ cnt, float* __restrict__ log_deg,
    double* __restrict__ avgacc)
{
  __shared__ double sb[256];
  int i = blockIdx.x * 256 + threadIdx.x;
  double c = 0.0;
  if (i < N_NODES) {
    int d = cnt[i];
    int dc = d > 0 ? d : 1;
    log_deg[i] = logf((float)dc + 1.0f);         // log(degc + 1)
    c = (double)logf((float)d + 1.0f);           // avg uses raw deg
  }
  sb[threadIdx.x] = c;
  __syncthreads();
  for (int off = 128; off > 0; off >>= 1) {
    if (threadIdx.x < off) sb[threadIdx.x] += sb[threadIdx.x + off];
    __syncthreads();
  }
  if (threadIdx.x == 0) atomicAdd(avgacc, sb[0]);
}

__global__ void finalize_avg_kernel(const double* __restrict__ avgacc,
                                    float* __restrict__ avgf)
{
  *avgf = (float)(*avgacc / (double)N_NODES);
}

// graph node counts from sorted batch via binary search
__global__ void gbound_kernel(const int* __restrict__ batch, int* __restrict__ gcnt)
{
  __shared__ int sb[65];
  int g = threadIdx.x;  // 64 threads
  int lo = 0, hi = N_NODES;
  while (lo < hi) { int mid = (lo + hi) >> 1; if (batch[mid] < g) lo = mid + 1; else hi = mid; }
  sb[g] = lo;
  if (g == 0) sb[64] = N_NODES;
  __syncthreads();
  gcnt[g] = sb[g + 1] - sb[g];
}

// ===================== weight prep: fold + transpose + bf16 hi/lo split =====
// Wt[l][col=192][k=576], col = s*64 + j. k<64 folds mean_d+mn_d+mx_d segs;
// k>=64 maps srcseg {1,2,4,5,7,8,10,11}. sd_d folded into beff (bprep).

__global__ __launch_bounds__(256) void wprep_kernel(
    const float* __restrict__ conv_w, unsigned short* __restrict__ wh,
    unsigned short* __restrict__ wl)
{
  int idx = blockIdx.x * 256 + threadIdx.x;   // 3*192*576 = 331776 = 1296*256
  int k = idx % 576;
  int c = (idx / 576) % 192;
  int l = idx / (576 * 192);
  int s = c >> 6, j = c & 63;
  const float* CW = conv_w + (size_t)l * 2304 * 64;
  float v;
  if (k < 64) {
    int base = s * 768 + k;
    v = CW[base * 64 + j] + CW[(base + 192) * 64 + j] + CW[(base + 384) * 64 + j];
  } else {
    const int srcseg[8] = {1, 2, 4, 5, 7, 8, 10, 11};
    int q = (k >> 6) - 1;
    int t = k & 63;
    v = CW[(s * 768 + srcseg[q] * 64 + t) * 64 + j];
  }
  unsigned short hh = f2bf_rne(v);
  wh[idx] = hh;
  wl[idx] = f2bf_rne(v - bf2f(hh));
}

__global__ void bprep_kernel(const float* __restrict__ conv_w, float* __restrict__ beff)
{
  int l = blockIdx.x;                 // 3 blocks x 192 threads
  int s = threadIdx.x >> 6, j = threadIdx.x & 63;
  const float* CW = conv_w + (size_t)l * 2304 * 64 + (size_t)(s * 768 + 576) * 64;
  float sum = 0.f;
#pragma unroll
  for (int t = 0; t < 64; t++) sum += CW[t * 64 + j];
  beff[(l * 3 + s) * 64 + j] = sum * 0.0031622776601683794f;   // sqrt(1e-5)
}

// ===================== aggregation: one wave per node, bf16 hi/lo out =======

__global__ __launch_bounds__(256) void agg_kernel(
    const float* __restrict__ x, const float* __restrict__ eattr,
    const float* __restrict__ edge_w, const float* __restrict__ edge_b,
    const int* __restrict__ row_ptr, const int2* __restrict__ pairs,
    unsigned short* __restrict__ agg_h, unsigned short* __restrict__ agg_l)
{
  int lane = threadIdx.x & 63;
  int n = blockIdx.x * 4 + (threadIdx.x >> 6);
  if (n >= N_NODES) return;

  float ew[16];
#pragma unroll
  for (int t = 0; t < 16; t++) ew[t] = edge_w[t * 64 + lane];
  float eb = edge_b[lane];
  float xd = x[n * 64 + lane];

  int s0 = row_ptr[n], s1 = row_ptr[n + 1];
  float sx = 0.f, qx = 0.f, mxx = -3.4e38f, mnx = 3.4e38f;
  float se = 0.f, qe = 0.f, mxe = -3.4e38f, mne = 3.4e38f;

  for (int j = s0; j < s1; j++) {
    int2 p = pairs[j];
    float xs = x[p.x * 64 + lane];
    float av = eattr[p.y * 16 + (lane & 15)];
    unsigned au = __float_as_uint(av);
    float ea = eb;
#pragma unroll
    for (int t = 0; t < 16; t++) {
      float a = __uint_as_float(__builtin_amdgcn_readlane(au, t));
      ea = fmaf(a, ew[t], ea);
    }
    sx += xs; qx = fmaf(xs, xs, qx);
    mxx = fmaxf(mxx, xs); mnx = fminf(mnx, xs);
    se += ea; qe = fmaf(ea, ea, qe);
    mxe = fmaxf(mxe, ea); mne = fminf(mne, ea);
  }

  int deg = s1 - s0;
  float degf = (float)deg;
  float inv = 1.0f / fmaxf(degf, 1.0f);
  bool has = deg > 0;

  float m_s  = sx * inv, ms_s = qx * inv;
  float sd_s = sqrtf(fmaxf(ms_s - m_s * m_s, 0.f) + 1e-5f);
  float mx_s = has ? mxx : 0.f, mn_s = has ? mnx : 0.f;

  float m_e  = se * inv, ms_e = qe * inv;
  float sd_e = sqrtf(fmaxf(ms_e - m_e * m_e, 0.f) + 1e-5f);
  float mx_e = has ? mxe : 0.f, mn_e = has ? mne : 0.f;

  unsigned short* bh = agg_h + (size_t)n * KEFF;
  unsigned short* bl = agg_l + (size_t)n * KEFF;
#define W2(off, val) { float _v = (val); unsigned short _h = f2bf_rne(_v); \
                       bh[(off) + lane] = _h; bl[(off) + lane] = f2bf_rne(_v - bf2f(_h)); }
  W2(0,   has ? xd : 0.f);
  W2(64,  m_s);  W2(128, m_e);
  W2(192, mn_s); W2(256, mn_e);
  W2(320, mx_s); W2(384, mx_e);
  W2(448, sd_s); W2(512, sd_e);
#undef W2
}

// ===================== MFMA GEMM: [N,576] @ [576,192], split-bf16 ==========
// D = Ah*Bh + Al*Bh + Ah*Bl (fp32-accurate). Block: 256 thr / 4 waves,
// M-tile 64 (4 mfrags of 16), wave w owns cols {w*16+s*64} so the amp/att
// segment combine is intra-lane. LDS stride 40 shorts = 80B (2-way bank
// aliasing: free). 16x16x32 bf16 MFMA; C/D: col=lane&15, row=quad*4+reg.

__global__ __launch_bounds__(256, 3) void gemm_kernel(
    const unsigned short* __restrict__ Ah, const unsigned short* __restrict__ Al,
    const unsigned short* __restrict__ Wh, const unsigned short* __restrict__ Wl,
    const float* __restrict__ beff, const float* __restrict__ bias,
    const float* __restrict__ log_deg, const float* __restrict__ avg_ptr,
    float* __restrict__ h)
{
  __shared__ __align__(16) short AsH[64 * 40], AsL[64 * 40];
  __shared__ __align__(16) short BsH[192 * 40], BsL[192 * 40];
  int tid = threadIdx.x;
  int lane = tid & 63, w = tid >> 6;
  int quad = lane >> 4, l15 = lane & 15;
  int n0 = blockIdx.x * 64;

  // A staging map: thread -> (row 0..63, chunk 0..3 of 8 bf16)
  int arow = tid >> 2, ac = tid & 3;
  int an = n0 + arow; if (an >= N_NODES) an = N_NODES - 1;
  const unsigned short* gah = Ah + (size_t)an * KEFF + ac * 8;
  const unsigned short* gal = Al + (size_t)an * KEFF + ac * 8;

  f32x4 acc[4][3] = {};

  for (int k0 = 0; k0 < KEFF; k0 += 32) {
    *(float4*)(AsH + arow * 40 + ac * 8) = *(const float4*)(gah + k0);
    *(float4*)(AsL + arow * 40 + ac * 8) = *(const float4*)(gal + k0);
#pragma unroll
    for (int q = 0; q < 6; q++) {
      int r = tid + (q < 3 ? q : q - 3) * 256;          // 0..767
      int col = r >> 2, cc = r & 3;
      const unsigned short* gb = (q < 3) ? Wh : Wl;
      short* bs = (q < 3) ? BsH : BsL;
      *(float4*)(bs + col * 40 + cc * 8) =
          *(const float4*)(gb + (size_t)col * KEFF + k0 + cc * 8);
    }
    __syncthreads();

    bf16x8 bh[3], bl[3];
#pragma unroll
    for (int s = 0; s < 3; s++) {
      int col = s * 64 + w * 16 + l15;
      bh[s] = *(const bf16x8*)(BsH + col * 40 + quad * 8);
      bl[s] = *(const bf16x8*)(BsL + col * 40 + quad * 8);
    }
#pragma unroll
    for (int i = 0; i < 4; i++) {
      int row = i * 16 + l15;
      bf16x8 ah = *(const bf16x8*)(AsH + row * 40 + quad * 8);
      bf16x8 al = *(const bf16x8*)(AsL + row * 40 + quad * 8);
#pragma unroll
      for (int s = 0; s < 3; s++) {
        acc[i][s] = __builtin_amdgcn_mfma_f32_16x16x32_bf16(ah, bh[s], acc[i][s], 0, 0, 0);
        acc[i][s] = __builtin_amdgcn_mfma_f32_16x16x32_bf16(al, bh[s], acc[i][s], 0, 0, 0);
        acc[i][s] = __builtin_amdgcn_mfma_f32_16x16x32_bf16(ah, bl[s], acc[i][s], 0, 0, 0);
      }
    }
    __syncthreads();
  }

  float avg = *avg_ptr;
  int col = w * 16 + l15;
  float be0 = beff[col], be1 = beff[64 + col], be2 = beff[128 + col];
  float bi = bias[col];
#pragma unroll
  for (int i = 0; i < 4; i++) {
#pragma unroll
    for (int r = 0; r < 4; r++) {
      int n = n0 + i * 16 + quad * 4 + r;
      if (n < N_NODES) {
        float ld = log_deg[n];
        float amp = ld / avg, att = avg / ld;
        float v = (acc[i][0][r] + be0) + amp * (acc[i][1][r] + be1)
                + att * (acc[i][2][r] + be2) + bi;
        h[(size_t)n * 64 + col] = v;
      }
    }
  }
}

// ===================== BatchNorm (training stats) =====================

__global__ __launch_bounds__(256) void bn_stats_kernel(
    const float* __restrict__ h, double* __restrict__ accS, double* __restrict__ accQ)
{
  __shared__ double sb[256], qb[256];
  int tid = threadIdx.x;
  int j = tid & 63, ri = tid >> 6;
  double s = 0.0, q = 0.0;
  for (int n = blockIdx.x * 4 + ri; n < N_NODES; n += 1024) {
    double v = (double)h[(size_t)n * 64 + j];
    s += v; q += v * v;
  }
  sb[tid] = s; qb[tid] = q;
  __syncthreads();
  if (tid < 64) {
    s = sb[tid] + sb[tid + 64] + sb[tid + 128] + sb[tid + 192];
    q = qb[tid] + qb[tid + 64] + qb[tid + 128] + qb[tid + 192];
    atomicAdd(&accS[j], s);
    atomicAdd(&accQ[j], q);
  }
}

__global__ void bn_finalize_kernel(const double* __restrict__ accS,
                                   const double* __restrict__ accQ,
                                   const float* __restrict__ g,
                                   float* __restrict__ muf, float* __restrict__ scf)
{
  int j = threadIdx.x;  // 64 threads
  double mu = accS[j] / (double)N_NODES;
  double var = accQ[j] / (double)N_NODES - mu * mu;
  double rstd = 1.0 / sqrt(var + 1e-5);
  muf[j] = (float)mu;
  scf[j] = (float)(rstd * (double)g[j]);
}

__global__ __launch_bounds__(256) void apply_kernel(
    const float* __restrict__ h, const float* __restrict__ muf,
    const float* __restrict__ scf, const float* __restrict__ bnb,
    float* __restrict__ x)
{
  int i4 = blockIdx.x * 256 + threadIdx.x;   // float4 index, exact grid
  const float4* h4 = (const float4*)h;
  float4* x4 = (float4*)x;
  int c4 = i4 & 15;
  float4 hv = h4[i4], xv = x4[i4];
  float4 mu = ((const float4*)muf)[c4];
  float4 sc = ((const float4*)scf)[c4];
  float4 bb = ((const float4*)bnb)[c4];
  float4 r;
  r.x = fmaxf((hv.x - mu.x) * sc.x + bb.x, 0.f) + xv.x;
  r.y = fmaxf((hv.y - mu.y) * sc.y + bb.y, 0.f) + xv.y;
  r.z = fmaxf((hv.z - mu.z) * sc.z + bb.z, 0.f) + xv.z;
  r.w = fmaxf((hv.w - mu.w) * sc.w + bb.w, 0.f) + xv.w;
  x4[i4] = r;
}

// ===================== pooling + head =====================

__global__ __launch_bounds__(256) void pool_kernel(
    const float* __restrict__ x, const int* __restrict__ batch,
    float* __restrict__ gsum)
{
  int tid = threadIdx.x;
  int j = tid & 63, ri = tid >> 6;
  float acc = 0.f; int cur = -1;
  for (int k = 0; k < 16; k++) {
    int n = blockIdx.x * 64 + k * 4 + ri;
    if (n < N_NODES) {
      int b = batch[n];
      if (b != cur) {
        if (cur >= 0) atomicAdd(&gsum[cur * 64 + j], acc);
        cur = b; acc = 0.f;
      }
      acc += x[(size_t)n * 64 + j];
    }
  }
  if (cur >= 0) atomicAdd(&gsum[cur * 64 + j], acc);
}

__global__ void fc_kernel(const float* __restrict__ gsum, const int* __restrict__ gcnt,
                          const float* __restrict__ w1, const float* __restrict__ b1,
                          const float* __restrict__ w2, const float* __restrict__ b2,
                          const float* __restrict__ w3, const float* __restrict__ b3,
                          float* __restrict__ out)
{
  int g = threadIdx.x;  // 64 threads, one per graph
  float cnt = fmaxf((float)gcnt[g], 1.0f);
  float gv[64];
#pragma unroll
  for (int j = 0; j < 64; j++) gv[j] = gsum[g * 64 + j] / cnt;
  float a1[32];
#pragma unroll
  for (int o = 0; o < 32; o++) {
    float s = b1[o];
#pragma unroll
    for (int j = 0; j < 64; j++) s = fmaf(gv[j], w1[j * 32 + o], s);
    a1[o] = fmaxf(s, 0.f);
  }
  float a2[16];
#pragma unroll
  for (int o = 0; o < 16; o++) {
    float s = b2[o];
#pragma unroll
    for (int j = 0; j < 32; j++) s = fmaf(a1[j], w2[j * 16 + o], s);
    a2[o] = fmaxf(s, 0.f);
  }
#pragma unroll
  for (int o = 0; o < 10; o++) {
    float s = b3[o];
#pragma unroll
    for (int j = 0; j < 16; j++) s = fmaf(a2[j], w3[j * 10 + o], s);
    out[g * 10 + o] = s;
  }
}

// ===================== launch =====================

extern "C" void kernel_launch(void* const* d_in, const int* in_sizes, int n_in,
                              void* d_out, int out_size, void* d_ws, size_t ws_size,
                              hipStream_t stream)
{
  (void)in_sizes; (void)n_in; (void)out_size; (void)ws_size;
  const float* xin    = (const float*)d_in[0];
  const int*   ei     = (const int*)d_in[1];
  const int*   batch  = (const int*)d_in[2];
  const float* eattr  = (const float*)d_in[3];
  const float* node_w = (const float*)d_in[4];
  const float* node_b = (const float*)d_in[5];
  const float* edge_w = (const float*)d_in[6];
  const float* edge_b = (const float*)d_in[7];
  const float* conv_w = (const float*)d_in[8];
  const float* conv_b = (const float*)d_in[9];
  const float* bn_g   = (const float*)d_in[10];
  const float* bn_b   = (const float*)d_in[11];
  const float* fc1_w  = (const float*)d_in[12];
  const float* fc1_b  = (const float*)d_in[13];
  const float* fc2_w  = (const float*)d_in[14];
  const float* fc2_b  = (const float*)d_in[15];
  const float* fc3_w  = (const float*)d_in[16];
  const float* fc3_b  = (const float*)d_in[17];
  float* out = (float*)d_out;
  const int* srcp = ei;
  const int* dstp = ei + N_EDGES;

  char* p = (char*)d_ws;
  auto alloc = [&](size_t b) { char* r = p; p += (b + 255) & ~(size_t)255; return (void*)r; };
  float*  x       = (float*)alloc((size_t)N_NODES * 64 * 4);
  float*  h       = (float*)alloc((size_t)N_NODES * 64 * 4);
  unsigned short* agg_h = (unsigned short*)alloc((size_t)N_NODES * KEFF * 2);
  unsigned short* agg_l = (unsigned short*)alloc((size_t)N_NODES * KEFF * 2);
  unsigned short* wh    = (unsigned short*)alloc((size_t)3 * 192 * KEFF * 2);
  unsigned short* wl    = (unsigned short*)alloc((size_t)3 * 192 * KEFF * 2);
  int2*   pairs   = (int2*)alloc((size_t)N_EDGES * 8);
  float*  beff    = (float*)alloc((size_t)3 * 3 * 64 * 4);
  int*    row_ptr = (int*)alloc((N_NODES + 1) * 4);
  int*    cursor  = (int*)alloc((size_t)N_NODES * 4);
  int*    cnt     = (int*)alloc((size_t)N_NODES * 4);
  float*  log_deg = (float*)alloc((size_t)N_NODES * 4);
  int*    bsum    = (int*)alloc(256 * 4);
  int*    boff    = (int*)alloc(256 * 4);
  double* avgacc  = (double*)alloc(256);
  float*  avgf    = (float*)alloc(256);
  double* bnacc   = (double*)alloc(128 * 8);
  float*  muf     = (float*)alloc(256);
  float*  scf     = (float*)alloc(256);
  float*  gsum    = (float*)alloc((size_t)NGRAPH * 64 * 4);
  int*    gcnt    = (int*)alloc((size_t)NGRAPH * 4);

  hipMemsetAsync(cnt, 0, (size_t)N_NODES * 4, stream);
  hipMemsetAsync(avgacc, 0, 8, stream);
  hipMemsetAsync(gsum, 0, (size_t)NGRAPH * 64 * 4, stream);

  node_enc_kernel<<<12500, 256, 0, stream>>>(xin, node_w, node_b, x);
  count_kernel<<<3125, 256, 0, stream>>>(dstp, cnt);
  scan_a_kernel<<<196, 256, 0, stream>>>(cnt, bsum);
  scan_b_kernel<<<1, 256, 0, stream>>>(bsum, boff);
  scan_c_kernel<<<196, 256, 0, stream>>>(cnt, boff, row_ptr);
  hipMemcpyAsync(cursor, row_ptr, (size_t)N_NODES * 4, hipMemcpyDeviceToDevice, stream);
  fill_kernel<<<3125, 256, 0, stream>>>(srcp, dstp, cursor, pairs);
  deg_log_kernel<<<196, 256, 0, stream>>>(cnt, log_deg, avgacc);
  finalize_avg_kernel<<<1, 1, 0, stream>>>(avgacc, avgf);
  gbound_kernel<<<1, 64, 0, stream>>>(batch, gcnt);
  wprep_kernel<<<1296, 256, 0, stream>>>(conv_w, wh, wl);
  bprep_kernel<<<3, 192, 0, stream>>>(conv_w, beff);

  for (int l = 0; l < 3; l++) {
    agg_kernel<<<12500, 256, 0, stream>>>(x, eattr, edge_w, edge_b, row_ptr, pairs,
                                          agg_h, agg_l);
    gemm_kernel<<<782, 256, 0, stream>>>(agg_h, agg_l,
                                         wh + (size_t)l * 192 * KEFF,
                                         wl + (size_t)l * 192 * KEFF,
                                         beff + l * 192, conv_b + l * 64,
                                         log_deg, avgf, h);
    hipMemsetAsync(bnacc, 0, 128 * 8, stream);
    bn_stats_kernel<<<256, 256, 0, stream>>>(h, bnacc, bnacc + 64);
    bn_finalize_kernel<<<1, 64, 0, stream>>>(bnacc, bnacc + 64, bn_g + l * 64, muf, scf);
    apply_kernel<<<3125, 256, 0, stream>>>(h, muf, scf, bn_b + l * 64, x);
  }

  pool_kernel<<<782, 256, 0, stream>>>(x, batch, gsum);
  fc_kernel<<<1, 64, 0, stream>>>(gsum, gcnt, fc1_w, fc1_b, fc2_w, fc2_b,
                                  fc3_w, fc3_b, out);
}

// Round 4
// 786.533 us; speedup vs baseline: 1.9644x; 1.1262x over previous
//
#include <hip/hip_runtime.h>
#include <math.h>

#define N_NODES 50000
#define N_EDGES 800000
#define NGRAPH  64
#define KEFF    576   // compressed agg width (768->576 via x_dst folding)

typedef short bf16x8 __attribute__((ext_vector_type(8)));
typedef float f32x4  __attribute__((ext_vector_type(4)));

__device__ inline unsigned short f2bf_rne(float f) {
  unsigned u = __float_as_uint(f);
  unsigned r = u + 0x7FFFu + ((u >> 16) & 1u);
  return (unsigned short)(r >> 16);
}
__device__ inline float bf2f(unsigned short h) {
  return __uint_as_float(((unsigned)h) << 16);
}

// ===================== setup kernels =====================

__global__ __launch_bounds__(256) void node_enc_kernel(
    const float* __restrict__ xin, const float* __restrict__ nw,
    const float* __restrict__ nb, float* __restrict__ x)
{
  __shared__ float xs[256];
  int tid = threadIdx.x;
  int base = blockIdx.x * 256;          // 4 nodes per block
  xs[tid] = xin[base + tid];
  __syncthreads();
  int r = tid >> 6, j = tid & 63;
  float acc = nb[j];
#pragma unroll
  for (int t = 0; t < 64; t++) acc = fmaf(xs[r * 64 + t], nw[t * 64 + j], acc);
  x[base + tid] = acc;
}

__global__ void count_kernel(const int* __restrict__ dst, int* __restrict__ cnt)
{
  int e = blockIdx.x * 256 + threadIdx.x;   // grid exactly covers E
  atomicAdd(&cnt[dst[e]], 1);
}

__global__ __launch_bounds__(256) void scan_a_kernel(
    const int* __restrict__ cnt, int* __restrict__ bsum)
{
  __shared__ int s[256];
  int i = blockIdx.x * 256 + threadIdx.x;
  s[threadIdx.x] = (i < N_NODES) ? cnt[i] : 0;
  __syncthreads();
  for (int off = 128; off > 0; off >>= 1) {
    if (threadIdx.x < off) s[threadIdx.x] += s[threadIdx.x + off];
    __syncthreads();
  }
  if (threadIdx.x == 0) bsum[blockIdx.x] = s[0];
}

__global__ __launch_bounds__(256) void scan_b_kernel(
    const int* __restrict__ bsum, int* __restrict__ boff)
{
  __shared__ int s[256];
  int tid = threadIdx.x;
  int v = (tid < 196) ? bsum[tid] : 0;
  s[tid] = v;
  __syncthreads();
  for (int off = 1; off < 256; off <<= 1) {
    int t = (tid >= off) ? s[tid - off] : 0;
    __syncthreads();
    s[tid] += t;
    __syncthreads();
  }
  boff[tid] = s[tid] - v;   // exclusive prefix of block sums
}

__global__ __launch_bounds__(256) void scan_c_kernel(
    const int* __restrict__ cnt, const int* __restrict__ boff,
    int* __restrict__ row_ptr)
{
  __shared__ int s[256];
  int tid = threadIdx.x;
  int i = blockIdx.x * 256 + tid;
  int v = (i < N_NODES) ? cnt[i] : 0;
  s[tid] = v;
  __syncthreads();
  for (int off = 1; off < 256; off <<= 1) {
    int t = (tid >= off) ? s[tid - off] : 0;
    __syncthreads();
    s[tid] += t;
    __syncthreads();
  }
  int incl = s[tid];
  int base = boff[blockIdx.x];
  if (i < N_NODES) row_ptr[i] = base + incl - v;
  if (i == N_NODES - 1) row_ptr[N_NODES] = base + incl;
}

__global__ void fill_kernel(const int* __restrict__ src, const int* __restrict__ dst,
                            int* __restrict__ cursor, int* __restrict__ srcs,
                            int* __restrict__ eids)
{
  int e = blockIdx.x * 256 + threadIdx.x;
  int d = dst[e];
  int pos = atomicAdd(&cursor[d], 1);
  srcs[pos] = src[e];
  eids[pos] = e;
}

__global__ __launch_bounds__(256) void deg_log_kernel(
    const int* __restrict__ cnt, float* __restrict__ log_deg,
    double* __restrict__ avgacc)
{
  __shared__ double sb[256];
  int i = blockIdx.x * 256 + threadIdx.x;
  double c = 0.0;
  if (i < N_NODES) {
    int d = cnt[i];
    int dc = d > 0 ? d : 1;
    log_deg[i] = logf((float)dc + 1.0f);         // log(degc + 1)
    c = (double)logf((float)d + 1.0f);           // avg uses raw deg
  }
  sb[threadIdx.x] = c;
  __syncthreads();
  for (int off = 128; off > 0; off >>= 1) {
    if (threadIdx.x < off) sb[threadIdx.x] += sb[threadIdx.x + off];
    __syncthreads();
  }
  if (threadIdx.x == 0) atomicAdd(avgacc, sb[0]);
}

__global__ void finalize_avg_kernel(const double* __restrict__ avgacc,
                                    float* __restrict__ avgf)
{
  *avgf = (float)(*avgacc / (double)N_NODES);
}

// graph node counts from sorted batch via binary search
__global__ void gbound_kernel(const int* __restrict__ batch, int* __restrict__ gcnt)
{
  __shared__ int sb[65];
  int g = threadIdx.x;  // 64 threads
  int lo = 0, hi = N_NODES;
  while (lo < hi) { int mid = (lo + hi) >> 1; if (batch[mid] < g) lo = mid + 1; else hi = mid; }
  sb[g] = lo;
  if (g == 0) sb[64] = N_NODES;
  __syncthreads();
  gcnt[g] = sb[g + 1] - sb[g];
}

// ===================== weight prep: fold + transpose + bf16 hi/lo split =====

__global__ __launch_bounds__(256) void wprep_kernel(
    const float* __restrict__ conv_w, unsigned short* __restrict__ wh,
    unsigned short* __restrict__ wl)
{
  int idx = blockIdx.x * 256 + threadIdx.x;   // 3*192*576 = 331776 = 1296*256
  int k = idx % 576;
  int c = (idx / 576) % 192;
  int l = idx / (576 * 192);
  int s = c >> 6, j = c & 63;
  const float* CW = conv_w + (size_t)l * 2304 * 64;
  float v;
  if (k < 64) {
    int base = s * 768 + k;
    v = CW[base * 64 + j] + CW[(base + 192) * 64 + j] + CW[(base + 384) * 64 + j];
  } else {
    const int srcseg[8] = {1, 2, 4, 5, 7, 8, 10, 11};
    int q = (k >> 6) - 1;
    int t = k & 63;
    v = CW[(s * 768 + srcseg[q] * 64 + t) * 64 + j];
  }
  unsigned short hh = f2bf_rne(v);
  wh[idx] = hh;
  wl[idx] = f2bf_rne(v - bf2f(hh));
}

__global__ void bprep_kernel(const float* __restrict__ conv_w, float* __restrict__ beff)
{
  int l = blockIdx.x;                 // 3 blocks x 192 threads
  int s = threadIdx.x >> 6, j = threadIdx.x & 63;
  const float* CW = conv_w + (size_t)l * 2304 * 64 + (size_t)(s * 768 + 576) * 64;
  float sum = 0.f;
#pragma unroll
  for (int t = 0; t < 64; t++) sum += CW[t * 64 + j];
  beff[(l * 3 + s) * 64 + j] = sum * 0.0031622776601683794f;   // sqrt(1e-5)
}

// ===================== edge-attr encoding (layer-invariant) =====================
// ea in CSR order: ea_sorted[j][lane]. One wave handles 16 CSR positions
// (amortizes the ew register load); coalesced 256B writes.

__global__ __launch_bounds__(256) void ea_kernel(
    const float* __restrict__ eattr, const int* __restrict__ eids,
    const float* __restrict__ edge_w, const float* __restrict__ edge_b,
    float* __restrict__ ea_sorted)
{
  int lane = threadIdx.x & 63, w = threadIdx.x >> 6;
  int base = blockIdx.x * 64 + w * 16;          // grid 12500 covers E exactly
  float ew[16];
#pragma unroll
  for (int t = 0; t < 16; t++) ew[t] = edge_w[t * 64 + lane];
  float eb = edge_b[lane];
  for (int t = 0; t < 16; t++) {
    int j = base + t;
    int e = eids[j];
    float av = eattr[(size_t)e * 16 + (lane & 15)];
    unsigned au = __float_as_uint(av);
    float ea0 = eb, ea1 = 0.f;                  // 2 chains for ILP
#pragma unroll
    for (int tt = 0; tt < 8; tt++)
      ea0 = fmaf(__uint_as_float(__builtin_amdgcn_readlane(au, tt)), ew[tt], ea0);
#pragma unroll
    for (int tt = 8; tt < 16; tt++)
      ea1 = fmaf(__uint_as_float(__builtin_amdgcn_readlane(au, tt)), ew[tt], ea1);
    ea_sorted[(size_t)j * 64 + lane] = ea0 + ea1;
  }
}

// e-segment aggregation from precomputed ea (coalesced streaming read)
__global__ __launch_bounds__(256) void agg_e_pre_kernel(
    const float* __restrict__ ea_sorted, const int* __restrict__ row_ptr,
    unsigned short* __restrict__ agg_h, unsigned short* __restrict__ agg_l)
{
  int lane = threadIdx.x & 63;
  int n = blockIdx.x * 4 + (threadIdx.x >> 6);
  if (n >= N_NODES) return;
  int s0 = row_ptr[n], s1 = row_ptr[n + 1];
  float se = 0.f, qe = 0.f, mxe = -3.4e38f, mne = 3.4e38f;
  int j = s0;
  for (; j + 1 < s1; j += 2) {
    float ea = ea_sorted[(size_t)j * 64 + lane];
    float eb = ea_sorted[(size_t)(j + 1) * 64 + lane];
    se += ea; qe = fmaf(ea, ea, qe); mxe = fmaxf(mxe, ea); mne = fminf(mne, ea);
    se += eb; qe = fmaf(eb, eb, qe); mxe = fmaxf(mxe, eb); mne = fminf(mne, eb);
  }
  if (j < s1) {
    float ea = ea_sorted[(size_t)j * 64 + lane];
    se += ea; qe = fmaf(ea, ea, qe); mxe = fmaxf(mxe, ea); mne = fminf(mne, ea);
  }
  int deg = s1 - s0;
  float inv = 1.0f / fmaxf((float)deg, 1.0f);
  bool has = deg > 0;
  float m_e = se * inv, ms_e = qe * inv;
  float sd_e = sqrtf(fmaxf(ms_e - m_e * m_e, 0.f) + 1e-5f);
  float mx_e = has ? mxe : 0.f, mn_e = has ? mne : 0.f;

  unsigned short* bh = agg_h + (size_t)n * KEFF;
  unsigned short* bl = agg_l + (size_t)n * KEFF;
#define W2(off, val) { float _v = (val); unsigned short _h = f2bf_rne(_v); \
                       bh[(off) + lane] = _h; bl[(off) + lane] = f2bf_rne(_v - bf2f(_h)); }
  W2(128, m_e); W2(256, mn_e); W2(384, mx_e); W2(512, sd_e);
#undef W2
}

// fallback: e-aggregation with on-the-fly ea recompute (if ws too small for ea_sorted)
__global__ __launch_bounds__(256) void agg_e_rec_kernel(
    const float* __restrict__ eattr, const float* __restrict__ edge_w,
    const float* __restrict__ edge_b, const int* __restrict__ row_ptr,
    const int* __restrict__ eids,
    unsigned short* __restrict__ agg_h, unsigned short* __restrict__ agg_l)
{
  int lane = threadIdx.x & 63;
  int n = blockIdx.x * 4 + (threadIdx.x >> 6);
  if (n >= N_NODES) return;
  float ew[16];
#pragma unroll
  for (int t = 0; t < 16; t++) ew[t] = edge_w[t * 64 + lane];
  float eb = edge_b[lane];
  int s0 = row_ptr[n], s1 = row_ptr[n + 1];
  float se = 0.f, qe = 0.f, mxe = -3.4e38f, mne = 3.4e38f;
  for (int j = s0; j < s1; j++) {
    int e = eids[j];
    float av = eattr[(size_t)e * 16 + (lane & 15)];
    unsigned au = __float_as_uint(av);
    float ea0 = eb, ea1 = 0.f;
#pragma unroll
    for (int tt = 0; tt < 8; tt++)
      ea0 = fmaf(__uint_as_float(__builtin_amdgcn_readlane(au, tt)), ew[tt], ea0);
#pragma unroll
    for (int tt = 8; tt < 16; tt++)
      ea1 = fmaf(__uint_as_float(__builtin_amdgcn_readlane(au, tt)), ew[tt], ea1);
    float ea = ea0 + ea1;
    se += ea; qe = fmaf(ea, ea, qe); mxe = fmaxf(mxe, ea); mne = fminf(mne, ea);
  }
  int deg = s1 - s0;
  float inv = 1.0f / fmaxf((float)deg, 1.0f);
  bool has = deg > 0;
  float m_e = se * inv, ms_e = qe * inv;
  float sd_e = sqrtf(fmaxf(ms_e - m_e * m_e, 0.f) + 1e-5f);
  float mx_e = has ? mxe : 0.f, mn_e = has ? mne : 0.f;
  unsigned short* bh = agg_h + (size_t)n * KEFF;
  unsigned short* bl = agg_l + (size_t)n * KEFF;
#define W2(off, val) { float _v = (val); unsigned short _h = f2bf_rne(_v); \
                       bh[(off) + lane] = _h; bl[(off) + lane] = f2bf_rne(_v - bf2f(_h)); }
  W2(128, m_e); W2(256, mn_e); W2(384, mx_e); W2(512, sd_e);
#undef W2
}

// ===================== per-layer x-segment aggregation =====================

__global__ __launch_bounds__(256) void agg_x_kernel(
    const float* __restrict__ x, const int* __restrict__ srcs,
    const int* __restrict__ row_ptr,
    unsigned short* __restrict__ agg_h, unsigned short* __restrict__ agg_l)
{
  int lane = threadIdx.x & 63;
  int n = blockIdx.x * 4 + (threadIdx.x >> 6);
  if (n >= N_NODES) return;
  float xd = x[(size_t)n * 64 + lane];
  int s0 = row_ptr[n], s1 = row_ptr[n + 1];
  float sx = 0.f, qx = 0.f, mxx = -3.4e38f, mnx = 3.4e38f;
  int j = s0;
  for (; j + 1 < s1; j += 2) {
    int sA = srcs[j], sB = srcs[j + 1];
    float xa = x[(size_t)sA * 64 + lane];
    float xb = x[(size_t)sB * 64 + lane];
    sx += xa; qx = fmaf(xa, xa, qx); mxx = fmaxf(mxx, xa); mnx = fminf(mnx, xa);
    sx += xb; qx = fmaf(xb, xb, qx); mxx = fmaxf(mxx, xb); mnx = fminf(mnx, xb);
  }
  if (j < s1) {
    float xa = x[(size_t)srcs[j] * 64 + lane];
    sx += xa; qx = fmaf(xa, xa, qx); mxx = fmaxf(mxx, xa); mnx = fminf(mnx, xa);
  }
  int deg = s1 - s0;
  float inv = 1.0f / fmaxf((float)deg, 1.0f);
  bool has = deg > 0;
  float m_s = sx * inv, ms_s = qx * inv;
  float sd_s = sqrtf(fmaxf(ms_s - m_s * m_s, 0.f) + 1e-5f);
  float mx_s = has ? mxx : 0.f, mn_s = has ? mnx : 0.f;

  unsigned short* bh = agg_h + (size_t)n * KEFF;
  unsigned short* bl = agg_l + (size_t)n * KEFF;
#define W2(off, val) { float _v = (val); unsigned short _h = f2bf_rne(_v); \
                       bh[(off) + lane] = _h; bl[(off) + lane] = f2bf_rne(_v - bf2f(_h)); }
  W2(0,   has ? xd : 0.f);
  W2(64,  m_s); W2(192, mn_s); W2(320, mx_s); W2(448, sd_s);
#undef W2
}

// ===================== MFMA GEMM + fused BN stats =====================
// D = Ah*Bh + Al*Bh + Ah*Bl (split-bf16 ~ fp32). 256 thr / 4 waves, M=64,
// N=192. C/D layout: col=lane&15, row=quad*4+reg -> amp/att combine intra-lane.
// BN sums: quad-shuffle reduce, f64 atomics into per-layer accumulators.

__global__ __launch_bounds__(256, 3) void gemm_kernel(
    const unsigned short* __restrict__ Ah, const unsigned short* __restrict__ Al,
    const unsigned short* __restrict__ Wh, const unsigned short* __restrict__ Wl,
    const float* __restrict__ beff, const float* __restrict__ bias,
    const float* __restrict__ log_deg, const float* __restrict__ avg_ptr,
    float* __restrict__ h, double* __restrict__ bnacc)
{
  __shared__ __align__(16) short AsH[64 * 40], AsL[64 * 40];
  __shared__ __align__(16) short BsH[192 * 40], BsL[192 * 40];
  int tid = threadIdx.x;
  int lane = tid & 63, w = tid >> 6;
  int quad = lane >> 4, l15 = lane & 15;
  int n0 = blockIdx.x * 64;

  int arow = tid >> 2, ac = tid & 3;
  int an = n0 + arow; if (an >= N_NODES) an = N_NODES - 1;
  const unsigned short* gah = Ah + (size_t)an * KEFF + ac * 8;
  const unsigned short* gal = Al + (size_t)an * KEFF + ac * 8;

  f32x4 acc[4][3] = {};

  for (int k0 = 0; k0 < KEFF; k0 += 32) {
    *(float4*)(AsH + arow * 40 + ac * 8) = *(const float4*)(gah + k0);
    *(float4*)(AsL + arow * 40 + ac * 8) = *(const float4*)(gal + k0);
#pragma unroll
    for (int q = 0; q < 6; q++) {
      int r = tid + (q < 3 ? q : q - 3) * 256;          // 0..767
      int col = r >> 2, cc = r & 3;
      const unsigned short* gb = (q < 3) ? Wh : Wl;
      short* bs = (q < 3) ? BsH : BsL;
      *(float4*)(bs + col * 40 + cc * 8) =
          *(const float4*)(gb + (size_t)col * KEFF + k0 + cc * 8);
    }
    __syncthreads();

    bf16x8 bh[3], bl[3];
#pragma unroll
    for (int s = 0; s < 3; s++) {
      int col = s * 64 + w * 16 + l15;
      bh[s] = *(const bf16x8*)(BsH + col * 40 + quad * 8);
      bl[s] = *(const bf16x8*)(BsL + col * 40 + quad * 8);
    }
#pragma unroll
    for (int i = 0; i < 4; i++) {
      int row = i * 16 + l15;
      bf16x8 ah = *(const bf16x8*)(AsH + row * 40 + quad * 8);
      bf16x8 al = *(const bf16x8*)(AsL + row * 40 + quad * 8);
#pragma unroll
      for (int s = 0; s < 3; s++) {
        acc[i][s] = __builtin_amdgcn_mfma_f32_16x16x32_bf16(ah, bh[s], acc[i][s], 0, 0, 0);
        acc[i][s] = __builtin_amdgcn_mfma_f32_16x16x32_bf16(al, bh[s], acc[i][s], 0, 0, 0);
        acc[i][s] = __builtin_amdgcn_mfma_f32_16x16x32_bf16(ah, bl[s], acc[i][s], 0, 0, 0);
      }
    }
    __syncthreads();
  }

  float avg = *avg_ptr;
  int col = w * 16 + l15;
  float be0 = beff[col], be1 = beff[64 + col], be2 = beff[128 + col];
  float bi = bias[col];
  float ss = 0.f, sq = 0.f;
#pragma unroll
  for (int i = 0; i < 4; i++) {
#pragma unroll
    for (int r = 0; r < 4; r++) {
      int n = n0 + i * 16 + quad * 4 + r;
      if (n < N_NODES) {
        float ld = log_deg[n];
        float amp = ld / avg, att = avg / ld;
        float v = (acc[i][0][r] + be0) + amp * (acc[i][1][r] + be1)
                + att * (acc[i][2][r] + be2) + bi;
        h[(size_t)n * 64 + col] = v;
        ss += v; sq = fmaf(v, v, sq);
      }
    }
  }
  // reduce over quads (same col every 16 lanes)
  ss += __shfl_xor(ss, 16, 64); ss += __shfl_xor(ss, 32, 64);
  sq += __shfl_xor(sq, 16, 64); sq += __shfl_xor(sq, 32, 64);
  if (quad == 0) {
    atomicAdd(&bnacc[col], (double)ss);
    atomicAdd(&bnacc[64 + col], (double)sq);
  }
}

// ===================== BatchNorm finalize + apply =====================

__global__ void bn_finalize_kernel(const double* __restrict__ accS,
                                   const double* __restrict__ accQ,
                                   const float* __restrict__ g,
                                   float* __restrict__ muf, float* __restrict__ scf)
{
  int j = threadIdx.x;  // 64 threads
  double mu = accS[j] / (double)N_NODES;
  double var = accQ[j] / (double)N_NODES - mu * mu;
  double rstd = 1.0 / sqrt(var + 1e-5);
  muf[j] = (float)mu;
  scf[j] = (float)(rstd * (double)g[j]);
}

__global__ __launch_bounds__(256) void apply_kernel(
    const float* __restrict__ h, const float* __restrict__ muf,
    const float* __restrict__ scf, const float* __restrict__ bnb,
    float* __restrict__ x)
{
  int i4 = blockIdx.x * 256 + threadIdx.x;   // float4 index, exact grid
  const float4* h4 = (const float4*)h;
  float4* x4 = (float4*)x;
  int c4 = i4 & 15;
  float4 hv = h4[i4], xv = x4[i4];
  float4 mu = ((const float4*)muf)[c4];
  float4 sc = ((const float4*)scf)[c4];
  float4 bb = ((const float4*)bnb)[c4];
  float4 r;
  r.x = fmaxf((hv.x - mu.x) * sc.x + bb.x, 0.f) + xv.x;
  r.y = fmaxf((hv.y - mu.y) * sc.y + bb.y, 0.f) + xv.y;
  r.z = fmaxf((hv.z - mu.z) * sc.z + bb.z, 0.f) + xv.z;
  r.w = fmaxf((hv.w - mu.w) * sc.w + bb.w, 0.f) + xv.w;
  x4[i4] = r;
}

// ===================== pooling + head =====================

__global__ __launch_bounds__(256) void pool_kernel(
    const float* __restrict__ x, const int* __restrict__ batch,
    float* __restrict__ gsum)
{
  int tid = threadIdx.x;
  int j = tid & 63, ri = tid >> 6;
  float acc = 0.f; int cur = -1;
  for (int k = 0; k < 16; k++) {
    int n = blockIdx.x * 64 + k * 4 + ri;
    if (n < N_NODES) {
      int b = batch[n];
      if (b != cur) {
        if (cur >= 0) atomicAdd(&gsum[cur * 64 + j], acc);
        cur = b; acc = 0.f;
      }
      acc += x[(size_t)n * 64 + j];
    }
  }
  if (cur >= 0) atomicAdd(&gsum[cur * 64 + j], acc);
}

__global__ void fc_kernel(const float* __restrict__ gsum, const int* __restrict__ gcnt,
                          const float* __restrict__ w1, const float* __restrict__ b1,
                          const float* __restrict__ w2, const float* __restrict__ b2,
                          const float* __restrict__ w3, const float* __restrict__ b3,
                          float* __restrict__ out)
{
  int g = threadIdx.x;  // 64 threads, one per graph
  float cnt = fmaxf((float)gcnt[g], 1.0f);
  float gv[64];
#pragma unroll
  for (int j = 0; j < 64; j++) gv[j] = gsum[g * 64 + j] / cnt;
  float a1[32];
#pragma unroll
  for (int o = 0; o < 32; o++) {
    float s = b1[o];
#pragma unroll
    for (int j = 0; j < 64; j++) s = fmaf(gv[j], w1[j * 32 + o], s);
    a1[o] = fmaxf(s, 0.f);
  }
  float a2[16];
#pragma unroll
  for (int o = 0; o < 16; o++) {
    float s = b2[o];
#pragma unroll
    for (int j = 0; j < 32; j++) s = fmaf(a1[j], w2[j * 16 + o], s);
    a2[o] = fmaxf(s, 0.f);
  }
#pragma unroll
  for (int o = 0; o < 10; o++) {
    float s = b3[o];
#pragma unroll
    for (int j = 0; j < 16; j++) s = fmaf(a2[j], w3[j * 10 + o], s);
    out[g * 10 + o] = s;
  }
}

// ===================== launch =====================

extern "C" void kernel_launch(void* const* d_in, const int* in_sizes, int n_in,
                              void* d_out, int out_size, void* d_ws, size_t ws_size,
                              hipStream_t stream)
{
  (void)in_sizes; (void)n_in; (void)out_size;
  const float* xin    = (const float*)d_in[0];
  const int*   ei     = (const int*)d_in[1];
  const int*   batch  = (const int*)d_in[2];
  const float* eattr  = (const float*)d_in[3];
  const float* node_w = (const float*)d_in[4];
  const float* node_b = (const float*)d_in[5];
  const float* edge_w = (const float*)d_in[6];
  const float* edge_b = (const float*)d_in[7];
  const float* conv_w = (const float*)d_in[8];
  const float* conv_b = (const float*)d_in[9];
  const float* bn_g   = (const float*)d_in[10];
  const float* bn_b   = (const float*)d_in[11];
  const float* fc1_w  = (const float*)d_in[12];
  const float* fc1_b  = (const float*)d_in[13];
  const float* fc2_w  = (const float*)d_in[14];
  const float* fc2_b  = (const float*)d_in[15];
  const float* fc3_w  = (const float*)d_in[16];
  const float* fc3_b  = (const float*)d_in[17];
  float* out = (float*)d_out;
  const int* srcp = ei;
  const int* dstp = ei + N_EDGES;

  char* p = (char*)d_ws;
  auto alloc = [&](size_t b) { char* r = p; p += (b + 255) & ~(size_t)255; return (void*)r; };
  float*  x       = (float*)alloc((size_t)N_NODES * 64 * 4);
  float*  h       = (float*)alloc((size_t)N_NODES * 64 * 4);
  unsigned short* agg_h = (unsigned short*)alloc((size_t)N_NODES * KEFF * 2);
  unsigned short* agg_l = (unsigned short*)alloc((size_t)N_NODES * KEFF * 2);
  unsigned short* wh    = (unsigned short*)alloc((size_t)3 * 192 * KEFF * 2);
  unsigned short* wl    = (unsigned short*)alloc((size_t)3 * 192 * KEFF * 2);
  int*    srcs    = (int*)alloc((size_t)N_EDGES * 4);
  int*    eids    = (int*)alloc((size_t)N_EDGES * 4);
  float*  beff    = (float*)alloc((size_t)3 * 3 * 64 * 4);
  int*    row_ptr = (int*)alloc((N_NODES + 1) * 4);
  int*    cursor  = (int*)alloc((size_t)N_NODES * 4);
  int*    cnt     = (int*)alloc((size_t)N_NODES * 4);
  float*  log_deg = (float*)alloc((size_t)N_NODES * 4);
  int*    bsum    = (int*)alloc(256 * 4);
  int*    boff    = (int*)alloc(256 * 4);
  double* avgacc  = (double*)alloc(256);
  float*  avgf    = (float*)alloc(256);
  double* bnacc   = (double*)alloc(3 * 128 * 8);
  float*  muf     = (float*)alloc(256);
  float*  scf     = (float*)alloc(256);
  float*  gsum    = (float*)alloc((size_t)NGRAPH * 64 * 4);
  int*    gcnt    = (int*)alloc((size_t)NGRAPH * 4);
  size_t base_used = (size_t)(p - (char*)d_ws);
  float* ea_sorted = (float*)p;   // optional 204.8 MB tail allocation
  bool useP = base_used + (size_t)N_EDGES * 64 * 4 <= ws_size;

  hipMemsetAsync(cnt, 0, (size_t)N_NODES * 4, stream);
  hipMemsetAsync(avgacc, 0, 8, stream);
  hipMemsetAsync(gsum, 0, (size_t)NGRAPH * 64 * 4, stream);
  hipMemsetAsync(bnacc, 0, 3 * 128 * 8, stream);

  node_enc_kernel<<<12500, 256, 0, stream>>>(xin, node_w, node_b, x);
  count_kernel<<<3125, 256, 0, stream>>>(dstp, cnt);
  scan_a_kernel<<<196, 256, 0, stream>>>(cnt, bsum);
  scan_b_kernel<<<1, 256, 0, stream>>>(bsum, boff);
  scan_c_kernel<<<196, 256, 0, stream>>>(cnt, boff, row_ptr);
  hipMemcpyAsync(cursor, row_ptr, (size_t)N_NODES * 4, hipMemcpyDeviceToDevice, stream);
  fill_kernel<<<3125, 256, 0, stream>>>(srcp, dstp, cursor, srcs, eids);
  deg_log_kernel<<<196, 256, 0, stream>>>(cnt, log_deg, avgacc);
  finalize_avg_kernel<<<1, 1, 0, stream>>>(avgacc, avgf);
  gbound_kernel<<<1, 64, 0, stream>>>(batch, gcnt);
  wprep_kernel<<<1296, 256, 0, stream>>>(conv_w, wh, wl);
  bprep_kernel<<<3, 192, 0, stream>>>(conv_w, beff);

  if (useP) {
    ea_kernel<<<12500, 256, 0, stream>>>(eattr, eids, edge_w, edge_b, ea_sorted);
    agg_e_pre_kernel<<<12500, 256, 0, stream>>>(ea_sorted, row_ptr, agg_h, agg_l);
  } else {
    agg_e_rec_kernel<<<12500, 256, 0, stream>>>(eattr, edge_w, edge_b, row_ptr,
                                                eids, agg_h, agg_l);
  }

  for (int l = 0; l < 3; l++) {
    agg_x_kernel<<<12500, 256, 0, stream>>>(x, srcs, row_ptr, agg_h, agg_l);
    gemm_kernel<<<782, 256, 0, stream>>>(agg_h, agg_l,
                                         wh + (size_t)l * 192 * KEFF,
                                         wl + (size_t)l * 192 * KEFF,
                                         beff + l * 192, conv_b + l * 64,
                                         log_deg, avgf, h, bnacc + l * 128);
    bn_finalize_kernel<<<1, 64, 0, stream>>>(bnacc + l * 128, bnacc + l * 128 + 64,
                                             bn_g + l * 64, muf, scf);
    apply_kernel<<<3125, 256, 0, stream>>>(h, muf, scf, bn_b + l * 64, x);
  }

  pool_kernel<<<782, 256, 0, stream>>>(x, batch, gsum);
  fc_kernel<<<1, 64, 0, stream>>>(gsum, gcnt, fc1_w, fc1_b, fc2_w, fc2_b,
                                  fc3_w, fc3_b, out);
}

// Round 5
// 706.421 us; speedup vs baseline: 2.1871x; 1.1134x over previous
//
#include <hip/hip_runtime.h>
#include <math.h>

#define N_NODES 50000
#define N_EDGES 800000
#define NGRAPH  64
#define KEFF    576   // compressed agg width (768->576 via x_dst folding)

typedef short bf16x8 __attribute__((ext_vector_type(8)));
typedef float f32x4  __attribute__((ext_vector_type(4)));

__device__ inline unsigned short f2bf_rne(float f) {
  unsigned u = __float_as_uint(f);
  unsigned r = u + 0x7FFFu + ((u >> 16) & 1u);
  return (unsigned short)(r >> 16);
}
__device__ inline float bf2f(unsigned short h) {
  return __uint_as_float(((unsigned)h) << 16);
}

// ===================== setup kernels =====================

__global__ __launch_bounds__(256) void node_enc_kernel(
    const float* __restrict__ xin, const float* __restrict__ nw,
    const float* __restrict__ nb, float* __restrict__ x)
{
  __shared__ float xs[256];
  int tid = threadIdx.x;
  int base = blockIdx.x * 256;          // 4 nodes per block
  xs[tid] = xin[base + tid];
  __syncthreads();
  int r = tid >> 6, j = tid & 63;
  float acc = nb[j];
#pragma unroll
  for (int t = 0; t < 64; t++) acc = fmaf(xs[r * 64 + t], nw[t * 64 + j], acc);
  x[base + tid] = acc;
}

__global__ void count_kernel(const int* __restrict__ dst, int* __restrict__ cnt)
{
  int e = blockIdx.x * 256 + threadIdx.x;   // grid exactly covers E
  atomicAdd(&cnt[dst[e]], 1);
}

__global__ __launch_bounds__(256) void scan_a_kernel(
    const int* __restrict__ cnt, int* __restrict__ bsum)
{
  __shared__ int s[256];
  int i = blockIdx.x * 256 + threadIdx.x;
  s[threadIdx.x] = (i < N_NODES) ? cnt[i] : 0;
  __syncthreads();
  for (int off = 128; off > 0; off >>= 1) {
    if (threadIdx.x < off) s[threadIdx.x] += s[threadIdx.x + off];
    __syncthreads();
  }
  if (threadIdx.x == 0) bsum[blockIdx.x] = s[0];
}

__global__ __launch_bounds__(256) void scan_b_kernel(
    const int* __restrict__ bsum, int* __restrict__ boff)
{
  __shared__ int s[256];
  int tid = threadIdx.x;
  int v = (tid < 196) ? bsum[tid] : 0;
  s[tid] = v;
  __syncthreads();
  for (int off = 1; off < 256; off <<= 1) {
    int t = (tid >= off) ? s[tid - off] : 0;
    __syncthreads();
    s[tid] += t;
    __syncthreads();
  }
  boff[tid] = s[tid] - v;   // exclusive prefix of block sums
}

__global__ __launch_bounds__(256) void scan_c_kernel(
    const int* __restrict__ cnt, const int* __restrict__ boff,
    int* __restrict__ row_ptr)
{
  __shared__ int s[256];
  int tid = threadIdx.x;
  int i = blockIdx.x * 256 + tid;
  int v = (i < N_NODES) ? cnt[i] : 0;
  s[tid] = v;
  __syncthreads();
  for (int off = 1; off < 256; off <<= 1) {
    int t = (tid >= off) ? s[tid - off] : 0;
    __syncthreads();
    s[tid] += t;
    __syncthreads();
  }
  int incl = s[tid];
  int base = boff[blockIdx.x];
  if (i < N_NODES) row_ptr[i] = base + incl - v;
  if (i == N_NODES - 1) row_ptr[N_NODES] = base + incl;
}

__global__ void fill_kernel(const int* __restrict__ src, const int* __restrict__ dst,
                            int* __restrict__ cursor, int* __restrict__ srcs,
                            int* __restrict__ eids)
{
  int e = blockIdx.x * 256 + threadIdx.x;
  int d = dst[e];
  int pos = atomicAdd(&cursor[d], 1);
  srcs[pos] = src[e];
  eids[pos] = e;
}

__global__ __launch_bounds__(256) void deg_log_kernel(
    const int* __restrict__ cnt, float* __restrict__ log_deg,
    double* __restrict__ avgacc)
{
  __shared__ double sb[256];
  int i = blockIdx.x * 256 + threadIdx.x;
  double c = 0.0;
  if (i < N_NODES) {
    int d = cnt[i];
    int dc = d > 0 ? d : 1;
    log_deg[i] = logf((float)dc + 1.0f);         // log(degc + 1)
    c = (double)logf((float)d + 1.0f);           // avg uses raw deg
  }
  sb[threadIdx.x] = c;
  __syncthreads();
  for (int off = 128; off > 0; off >>= 1) {
    if (threadIdx.x < off) sb[threadIdx.x] += sb[threadIdx.x + off];
    __syncthreads();
  }
  if (threadIdx.x == 0) atomicAdd(avgacc, sb[0]);
}

__global__ void finalize_avg_kernel(const double* __restrict__ avgacc,
                                    float* __restrict__ avgf)
{
  *avgf = (float)(*avgacc / (double)N_NODES);
}

// graph node counts from sorted batch via binary search
__global__ void gbound_kernel(const int* __restrict__ batch, int* __restrict__ gcnt)
{
  __shared__ int sb[65];
  int g = threadIdx.x;  // 64 threads
  int lo = 0, hi = N_NODES;
  while (lo < hi) { int mid = (lo + hi) >> 1; if (batch[mid] < g) lo = mid + 1; else hi = mid; }
  sb[g] = lo;
  if (g == 0) sb[64] = N_NODES;
  __syncthreads();
  gcnt[g] = sb[g + 1] - sb[g];
}

// ===================== weight prep: fold + transpose + bf16 hi/lo split =====

__global__ __launch_bounds__(256) void wprep_kernel(
    const float* __restrict__ conv_w, unsigned short* __restrict__ wh,
    unsigned short* __restrict__ wl)
{
  int idx = blockIdx.x * 256 + threadIdx.x;   // 3*192*576 = 331776 = 1296*256
  int k = idx % 576;
  int c = (idx / 576) % 192;
  int l = idx / (576 * 192);
  int s = c >> 6, j = c & 63;
  const float* CW = conv_w + (size_t)l * 2304 * 64;
  float v;
  if (k < 64) {
    int base = s * 768 + k;
    v = CW[base * 64 + j] + CW[(base + 192) * 64 + j] + CW[(base + 384) * 64 + j];
  } else {
    const int srcseg[8] = {1, 2, 4, 5, 7, 8, 10, 11};
    int q = (k >> 6) - 1;
    int t = k & 63;
    v = CW[(s * 768 + srcseg[q] * 64 + t) * 64 + j];
  }
  unsigned short hh = f2bf_rne(v);
  wh[idx] = hh;
  wl[idx] = f2bf_rne(v - bf2f(hh));
}

__global__ void bprep_kernel(const float* __restrict__ conv_w, float* __restrict__ beff)
{
  int l = blockIdx.x;                 // 3 blocks x 192 threads
  int s = threadIdx.x >> 6, j = threadIdx.x & 63;
  const float* CW = conv_w + (size_t)l * 2304 * 64 + (size_t)(s * 768 + 576) * 64;
  float sum = 0.f;
#pragma unroll
  for (int t = 0; t < 64; t++) sum += CW[t * 64 + j];
  beff[(l * 3 + s) * 64 + j] = sum * 0.0031622776601683794f;   // sqrt(1e-5)
}

// ===================== e-segment aggregation (layer-invariant, once) ========
// 4 edges per iteration: lane-quad q holds edge (j+q)'s 16 attrs -> one
// full-wave gather; 4 independent chains (x2 sub-chains) for ILP.

__global__ __launch_bounds__(256) void agg_e_kernel(
    const float* __restrict__ eattr, const float* __restrict__ edge_w,
    const float* __restrict__ edge_b, const int* __restrict__ row_ptr,
    const int* __restrict__ eids,
    unsigned short* __restrict__ agg_h, unsigned short* __restrict__ agg_l)
{
  int lane = threadIdx.x & 63;
  int quad = lane >> 4, a16 = lane & 15;
  int n = blockIdx.x * 4 + (threadIdx.x >> 6);
  if (n >= N_NODES) return;
  float ew[16];
#pragma unroll
  for (int t = 0; t < 16; t++) ew[t] = edge_w[t * 64 + lane];
  float eb = edge_b[lane];
  int s0 = row_ptr[n], s1 = row_ptr[n + 1];
  float se = 0.f, qe = 0.f, mxe = -3.4e38f, mne = 3.4e38f;

  for (int j = s0; j < s1; j += 4) {
    int idx = j + quad;
    float av = 0.f;
    if (idx < s1) av = eattr[(size_t)eids[idx] * 16 + a16];
    unsigned au = __float_as_uint(av);
    float ea[4];
#pragma unroll
    for (int q = 0; q < 4; q++) {
      float c0 = eb, c1 = 0.f;
#pragma unroll
      for (int t = 0; t < 8; t++) {
        c0 = fmaf(__uint_as_float(__builtin_amdgcn_readlane(au, q * 16 + t)), ew[t], c0);
        c1 = fmaf(__uint_as_float(__builtin_amdgcn_readlane(au, q * 16 + 8 + t)), ew[8 + t], c1);
      }
      ea[q] = c0 + c1;
    }
    int rem = s1 - j;   // wave-uniform
#pragma unroll
    for (int q = 0; q < 4; q++) {
      if (q < rem) {
        se += ea[q]; qe = fmaf(ea[q], ea[q], qe);
        mxe = fmaxf(mxe, ea[q]); mne = fminf(mne, ea[q]);
      }
    }
  }

  int deg = s1 - s0;
  float inv = 1.0f / fmaxf((float)deg, 1.0f);
  bool has = deg > 0;
  float m_e = se * inv, ms_e = qe * inv;
  float sd_e = sqrtf(fmaxf(ms_e - m_e * m_e, 0.f) + 1e-5f);
  float mx_e = has ? mxe : 0.f, mn_e = has ? mne : 0.f;

  unsigned short* bh = agg_h + (size_t)n * KEFF;
  unsigned short* bl = agg_l + (size_t)n * KEFF;
#define W2(off, val) { float _v = (val); unsigned short _h = f2bf_rne(_v); \
                       bh[(off) + lane] = _h; bl[(off) + lane] = f2bf_rne(_v - bf2f(_h)); }
  W2(128, m_e); W2(256, mn_e); W2(384, mx_e); W2(512, sd_e);
#undef W2
}

// ===================== per-layer x-segment aggregation =====================
// x4 unroll: 4 gathers in flight, 4 independent accumulator chains.

__global__ __launch_bounds__(256) void agg_x_kernel(
    const float* __restrict__ x, const int* __restrict__ srcs,
    const int* __restrict__ row_ptr,
    unsigned short* __restrict__ agg_h, unsigned short* __restrict__ agg_l)
{
  int lane = threadIdx.x & 63;
  int n = blockIdx.x * 4 + (threadIdx.x >> 6);
  if (n >= N_NODES) return;
  float xd = x[(size_t)n * 64 + lane];
  int s0 = row_ptr[n], s1 = row_ptr[n + 1];
  float sA = 0.f, sB = 0.f, sC = 0.f, sD = 0.f;
  float qA = 0.f, qB = 0.f, qC = 0.f, qD = 0.f;
  float mx0 = -3.4e38f, mx1 = -3.4e38f, mn0 = 3.4e38f, mn1 = 3.4e38f;
  int j = s0;
  for (; j + 3 < s1; j += 4) {
    int e0 = srcs[j], e1 = srcs[j + 1], e2 = srcs[j + 2], e3 = srcs[j + 3];
    float xa = x[(size_t)e0 * 64 + lane];
    float xb = x[(size_t)e1 * 64 + lane];
    float xc = x[(size_t)e2 * 64 + lane];
    float xe = x[(size_t)e3 * 64 + lane];
    sA += xa; sB += xb; sC += xc; sD += xe;
    qA = fmaf(xa, xa, qA); qB = fmaf(xb, xb, qB);
    qC = fmaf(xc, xc, qC); qD = fmaf(xe, xe, qD);
    mx0 = fmaxf(mx0, fmaxf(xa, xb)); mx1 = fmaxf(mx1, fmaxf(xc, xe));
    mn0 = fminf(mn0, fminf(xa, xb)); mn1 = fminf(mn1, fminf(xc, xe));
  }
  for (; j < s1; j++) {
    float xa = x[(size_t)srcs[j] * 64 + lane];
    sA += xa; qA = fmaf(xa, xa, qA);
    mx0 = fmaxf(mx0, xa); mn0 = fminf(mn0, xa);
  }
  float sx = (sA + sB) + (sC + sD);
  float qx = (qA + qB) + (qC + qD);
  float mxx = fmaxf(mx0, mx1), mnx = fminf(mn0, mn1);

  int deg = s1 - s0;
  float inv = 1.0f / fmaxf((float)deg, 1.0f);
  bool has = deg > 0;
  float m_s = sx * inv, ms_s = qx * inv;
  float sd_s = sqrtf(fmaxf(ms_s - m_s * m_s, 0.f) + 1e-5f);
  float mx_s = has ? mxx : 0.f, mn_s = has ? mnx : 0.f;

  unsigned short* bh = agg_h + (size_t)n * KEFF;
  unsigned short* bl = agg_l + (size_t)n * KEFF;
#define W2(off, val) { float _v = (val); unsigned short _h = f2bf_rne(_v); \
                       bh[(off) + lane] = _h; bl[(off) + lane] = f2bf_rne(_v - bf2f(_h)); }
  W2(0,   has ? xd : 0.f);
  W2(64,  m_s); W2(192, mn_s); W2(320, mx_s); W2(448, sd_s);
#undef W2
}

// ===================== MFMA GEMM + fused BN stats =====================
// D = Ah*Bh + Al*Bh + Ah*Bl (split-bf16 ~ fp32). 256 thr / 4 waves, M=64,
// N=192. C/D layout: col=lane&15, row=quad*4+reg -> amp/att combine intra-lane.

__global__ __launch_bounds__(256, 3) void gemm_kernel(
    const unsigned short* __restrict__ Ah, const unsigned short* __restrict__ Al,
    const unsigned short* __restrict__ Wh, const unsigned short* __restrict__ Wl,
    const float* __restrict__ beff, const float* __restrict__ bias,
    const float* __restrict__ log_deg, const float* __restrict__ avg_ptr,
    float* __restrict__ h, double* __restrict__ bnacc)
{
  __shared__ __align__(16) short AsH[64 * 40], AsL[64 * 40];
  __shared__ __align__(16) short BsH[192 * 40], BsL[192 * 40];
  int tid = threadIdx.x;
  int lane = tid & 63, w = tid >> 6;
  int quad = lane >> 4, l15 = lane & 15;
  int n0 = blockIdx.x * 64;

  int arow = tid >> 2, ac = tid & 3;
  int an = n0 + arow; if (an >= N_NODES) an = N_NODES - 1;
  const unsigned short* gah = Ah + (size_t)an * KEFF + ac * 8;
  const unsigned short* gal = Al + (size_t)an * KEFF + ac * 8;

  f32x4 acc[4][3] = {};

  for (int k0 = 0; k0 < KEFF; k0 += 32) {
    *(float4*)(AsH + arow * 40 + ac * 8) = *(const float4*)(gah + k0);
    *(float4*)(AsL + arow * 40 + ac * 8) = *(const float4*)(gal + k0);
#pragma unroll
    for (int q = 0; q < 6; q++) {
      int r = tid + (q < 3 ? q : q - 3) * 256;          // 0..767
      int col = r >> 2, cc = r & 3;
      const unsigned short* gb = (q < 3) ? Wh : Wl;
      short* bs = (q < 3) ? BsH : BsL;
      *(float4*)(bs + col * 40 + cc * 8) =
          *(const float4*)(gb + (size_t)col * KEFF + k0 + cc * 8);
    }
    __syncthreads();

    bf16x8 bh[3], bl[3];
#pragma unroll
    for (int s = 0; s < 3; s++) {
      int col = s * 64 + w * 16 + l15;
      bh[s] = *(const bf16x8*)(BsH + col * 40 + quad * 8);
      bl[s] = *(const bf16x8*)(BsL + col * 40 + quad * 8);
    }
#pragma unroll
    for (int i = 0; i < 4; i++) {
      int row = i * 16 + l15;
      bf16x8 ah = *(const bf16x8*)(AsH + row * 40 + quad * 8);
      bf16x8 al = *(const bf16x8*)(AsL + row * 40 + quad * 8);
#pragma unroll
      for (int s = 0; s < 3; s++) {
        acc[i][s] = __builtin_amdgcn_mfma_f32_16x16x32_bf16(ah, bh[s], acc[i][s], 0, 0, 0);
        acc[i][s] = __builtin_amdgcn_mfma_f32_16x16x32_bf16(al, bh[s], acc[i][s], 0, 0, 0);
        acc[i][s] = __builtin_amdgcn_mfma_f32_16x16x32_bf16(ah, bl[s], acc[i][s], 0, 0, 0);
      }
    }
    __syncthreads();
  }

  float avg = *avg_ptr;
  int col = w * 16 + l15;
  float be0 = beff[col], be1 = beff[64 + col], be2 = beff[128 + col];
  float bi = bias[col];
  float ss = 0.f, sq = 0.f;
#pragma unroll
  for (int i = 0; i < 4; i++) {
#pragma unroll
    for (int r = 0; r < 4; r++) {
      int n = n0 + i * 16 + quad * 4 + r;
      if (n < N_NODES) {
        float ld = log_deg[n];
        float amp = ld / avg, att = avg / ld;
        float v = (acc[i][0][r] + be0) + amp * (acc[i][1][r] + be1)
                + att * (acc[i][2][r] + be2) + bi;
        h[(size_t)n * 64 + col] = v;
        ss += v; sq = fmaf(v, v, sq);
      }
    }
  }
  // reduce over quads (same col every 16 lanes)
  ss += __shfl_xor(ss, 16, 64); ss += __shfl_xor(ss, 32, 64);
  sq += __shfl_xor(sq, 16, 64); sq += __shfl_xor(sq, 32, 64);
  if (quad == 0) {
    atomicAdd(&bnacc[col], (double)ss);
    atomicAdd(&bnacc[64 + col], (double)sq);
  }
}

// ===================== BatchNorm finalize + apply =====================

__global__ void bn_finalize_kernel(const double* __restrict__ accS,
                                   const double* __restrict__ accQ,
                                   const float* __restrict__ g,
                                   float* __restrict__ muf, float* __restrict__ scf)
{
  int j = threadIdx.x;  // 64 threads
  double mu = accS[j] / (double)N_NODES;
  double var = accQ[j] / (double)N_NODES - mu * mu;
  double rstd = 1.0 / sqrt(var + 1e-5);
  muf[j] = (float)mu;
  scf[j] = (float)(rstd * (double)g[j]);
}

__global__ __launch_bounds__(256) void apply_kernel(
    const float* __restrict__ h, const float* __restrict__ muf,
    const float* __restrict__ scf, const float* __restrict__ bnb,
    float* __restrict__ x)
{
  int i4 = blockIdx.x * 256 + threadIdx.x;   // float4 index, exact grid
  const float4* h4 = (const float4*)h;
  float4* x4 = (float4*)x;
  int c4 = i4 & 15;
  float4 hv = h4[i4], xv = x4[i4];
  float4 mu = ((const float4*)muf)[c4];
  float4 sc = ((const float4*)scf)[c4];
  float4 bb = ((const float4*)bnb)[c4];
  float4 r;
  r.x = fmaxf((hv.x - mu.x) * sc.x + bb.x, 0.f) + xv.x;
  r.y = fmaxf((hv.y - mu.y) * sc.y + bb.y, 0.f) + xv.y;
  r.z = fmaxf((hv.z - mu.z) * sc.z + bb.z, 0.f) + xv.z;
  r.w = fmaxf((hv.w - mu.w) * sc.w + bb.w, 0.f) + xv.w;
  x4[i4] = r;
}

// ===================== pooling + head =====================

__global__ __launch_bounds__(256) void pool_kernel(
    const float* __restrict__ x, const int* __restrict__ batch,
    float* __restrict__ gsum)
{
  int tid = threadIdx.x;
  int j = tid & 63, ri = tid >> 6;
  float acc = 0.f; int cur = -1;
  for (int k = 0; k < 16; k++) {
    int n = blockIdx.x * 64 + k * 4 + ri;
    if (n < N_NODES) {
      int b = batch[n];
      if (b != cur) {
        if (cur >= 0) atomicAdd(&gsum[cur * 64 + j], acc);
        cur = b; acc = 0.f;
      }
      acc += x[(size_t)n * 64 + j];
    }
  }
  if (cur >= 0) atomicAdd(&gsum[cur * 64 + j], acc);
}

__global__ void fc_kernel(const float* __restrict__ gsum, const int* __restrict__ gcnt,
                          const float* __restrict__ w1, const float* __restrict__ b1,
                          const float* __restrict__ w2, const float* __restrict__ b2,
                          const float* __restrict__ w3, const float* __restrict__ b3,
                          float* __restrict__ out)
{
  int g = threadIdx.x;  // 64 threads, one per graph
  float cnt = fmaxf((float)gcnt[g], 1.0f);
  float gv[64];
#pragma unroll
  for (int j = 0; j < 64; j++) gv[j] = gsum[g * 64 + j] / cnt;
  float a1[32];
#pragma unroll
  for (int o = 0; o < 32; o++) {
    float s = b1[o];
#pragma unroll
    for (int j = 0; j < 64; j++) s = fmaf(gv[j], w1[j * 32 + o], s);
    a1[o] = fmaxf(s, 0.f);
  }
  float a2[16];
#pragma unroll
  for (int o = 0; o < 16; o++) {
    float s = b2[o];
#pragma unroll
    for (int j = 0; j < 32; j++) s = fmaf(a1[j], w2[j * 16 + o], s);
    a2[o] = fmaxf(s, 0.f);
  }
#pragma unroll
  for (int o = 0; o < 10; o++) {
    float s = b3[o];
#pragma unroll
    for (int j = 0; j < 16; j++) s = fmaf(a2[j], w3[j * 10 + o], s);
    out[g * 10 + o] = s;
  }
}

// ===================== launch =====================

extern "C" void kernel_launch(void* const* d_in, const int* in_sizes, int n_in,
                              void* d_out, int out_size, void* d_ws, size_t ws_size,
                              hipStream_t stream)
{
  (void)in_sizes; (void)n_in; (void)out_size; (void)ws_size;
  const float* xin    = (const float*)d_in[0];
  const int*   ei     = (const int*)d_in[1];
  const int*   batch  = (const int*)d_in[2];
  const float* eattr  = (const float*)d_in[3];
  const float* node_w = (const float*)d_in[4];
  const float* node_b = (const float*)d_in[5];
  const float* edge_w = (const float*)d_in[6];
  const float* edge_b = (const float*)d_in[7];
  const float* conv_w = (const float*)d_in[8];
  const float* conv_b = (const float*)d_in[9];
  const float* bn_g   = (const float*)d_in[10];
  const float* bn_b   = (const float*)d_in[11];
  const float* fc1_w  = (const float*)d_in[12];
  const float* fc1_b  = (const float*)d_in[13];
  const float* fc2_w  = (const float*)d_in[14];
  const float* fc2_b  = (const float*)d_in[15];
  const float* fc3_w  = (const float*)d_in[16];
  const float* fc3_b  = (const float*)d_in[17];
  float* out = (float*)d_out;
  const int* srcp = ei;
  const int* dstp = ei + N_EDGES;

  char* p = (char*)d_ws;
  auto alloc = [&](size_t b) { char* r = p; p += (b + 255) & ~(size_t)255; return (void*)r; };
  float*  x       = (float*)alloc((size_t)N_NODES * 64 * 4);
  float*  h       = (float*)alloc((size_t)N_NODES * 64 * 4);
  unsigned short* agg_h = (unsigned short*)alloc((size_t)N_NODES * KEFF * 2);
  unsigned short* agg_l = (unsigned short*)alloc((size_t)N_NODES * KEFF * 2);
  unsigned short* wh    = (unsigned short*)alloc((size_t)3 * 192 * KEFF * 2);
  unsigned short* wl    = (unsigned short*)alloc((size_t)3 * 192 * KEFF * 2);
  int*    srcs    = (int*)alloc((size_t)N_EDGES * 4);
  int*    eids    = (int*)alloc((size_t)N_EDGES * 4);
  float*  beff    = (float*)alloc((size_t)3 * 3 * 64 * 4);
  int*    row_ptr = (int*)alloc((N_NODES + 1) * 4);
  int*    cursor  = (int*)alloc((size_t)N_NODES * 4);
  int*    cnt     = (int*)alloc((size_t)N_NODES * 4);
  float*  log_deg = (float*)alloc((size_t)N_NODES * 4);
  int*    bsum    = (int*)alloc(256 * 4);
  int*    boff    = (int*)alloc(256 * 4);
  double* avgacc  = (double*)alloc(256);
  float*  avgf    = (float*)alloc(256);
  double* bnacc   = (double*)alloc(3 * 128 * 8);
  float*  muf     = (float*)alloc(256);
  float*  scf     = (float*)alloc(256);
  float*  gsum    = (float*)alloc((size_t)NGRAPH * 64 * 4);
  int*    gcnt    = (int*)alloc((size_t)NGRAPH * 4);

  hipMemsetAsync(cnt, 0, (size_t)N_NODES * 4, stream);
  hipMemsetAsync(avgacc, 0, 8, stream);
  hipMemsetAsync(gsum, 0, (size_t)NGRAPH * 64 * 4, stream);
  hipMemsetAsync(bnacc, 0, 3 * 128 * 8, stream);

  node_enc_kernel<<<12500, 256, 0, stream>>>(xin, node_w, node_b, x);
  count_kernel<<<3125, 256, 0, stream>>>(dstp, cnt);
  scan_a_kernel<<<196, 256, 0, stream>>>(cnt, bsum);
  scan_b_kernel<<<1, 256, 0, stream>>>(bsum, boff);
  scan_c_kernel<<<196, 256, 0, stream>>>(cnt, boff, row_ptr);
  hipMemcpyAsync(cursor, row_ptr, (size_t)N_NODES * 4, hipMemcpyDeviceToDevice, stream);
  fill_kernel<<<3125, 256, 0, stream>>>(srcp, dstp, cursor, srcs, eids);
  deg_log_kernel<<<196, 256, 0, stream>>>(cnt, log_deg, avgacc);
  finalize_avg_kernel<<<1, 1, 0, stream>>>(avgacc, avgf);
  gbound_kernel<<<1, 64, 0, stream>>>(batch, gcnt);
  wprep_kernel<<<1296, 256, 0, stream>>>(conv_w, wh, wl);
  bprep_kernel<<<3, 192, 0, stream>>>(conv_w, beff);

  agg_e_kernel<<<12500, 256, 0, stream>>>(eattr, edge_w, edge_b, row_ptr,
                                          eids, agg_h, agg_l);

  for (int l = 0; l < 3; l++) {
    agg_x_kernel<<<12500, 256, 0, stream>>>(x, srcs, row_ptr, agg_h, agg_l);
    gemm_kernel<<<782, 256, 0, stream>>>(agg_h, agg_l,
                                         wh + (size_t)l * 192 * KEFF,
                                         wl + (size_t)l * 192 * KEFF,
                                         beff + l * 192, conv_b + l * 64,
                                         log_deg, avgf, h, bnacc + l * 128);
    bn_finalize_kernel<<<1, 64, 0, stream>>>(bnacc + l * 128, bnacc + l * 128 + 64,
                                             bn_g + l * 64, muf, scf);
    apply_kernel<<<3125, 256, 0, stream>>>(h, muf, scf, bn_b + l * 64, x);
  }

  pool_kernel<<<782, 256, 0, stream>>>(x, batch, gsum);
  fc_kernel<<<1, 64, 0, stream>>>(gsum, gcnt, fc1_w, fc1_b, fc2_w, fc2_b,
                                  fc3_w, fc3_b, out);
}

// Round 6
// 693.967 us; speedup vs baseline: 2.2264x; 1.0179x over previous
//
#include <hip/hip_runtime.h>
#include <math.h>

#define N_NODES 50000
#define N_EDGES 800000
#define NGRAPH  64
#define KEFF    576   // compressed agg width (768->576 via x_dst folding)

typedef short bf16x8 __attribute__((ext_vector_type(8)));
typedef float f32x4  __attribute__((ext_vector_type(4)));

union U8 { bf16x8 v; unsigned u[4]; };

__device__ inline unsigned short f2bf_rne(float f) {
  unsigned u = __float_as_uint(f);
  unsigned r = u + 0x7FFFu + ((u >> 16) & 1u);
  return (unsigned short)(r >> 16);
}
__device__ inline float bf2f(unsigned short h) {
  return __uint_as_float(((unsigned)h) << 16);
}

// pack 8 floats into hi/lo bf16x8 via truncation split (err ~2^-17 rel)
__device__ inline void split8(const float* a, bf16x8& H, bf16x8& L) {
  U8 hh, ll;
#pragma unroll
  for (int p = 0; p < 4; p++) {
    unsigned u0 = __float_as_uint(a[2 * p]);
    unsigned u1 = __float_as_uint(a[2 * p + 1]);
    unsigned h0 = u0 & 0xFFFF0000u, h1 = u1 & 0xFFFF0000u;
    hh.u[p] = (h0 >> 16) | h1;
    float r0 = a[2 * p] - __uint_as_float(h0);
    float r1 = a[2 * p + 1] - __uint_as_float(h1);
    ll.u[p] = ((__float_as_uint(r0) & 0xFFFF0000u) >> 16)
            | (__float_as_uint(r1) & 0xFFFF0000u);
  }
  H = hh.v; L = ll.v;
}

// ===================== setup kernels =====================

__global__ __launch_bounds__(256) void node_enc_kernel(
    const float* __restrict__ xin, const float* __restrict__ nw,
    const float* __restrict__ nb, float* __restrict__ x)
{
  __shared__ float xs[256];
  int tid = threadIdx.x;
  int base = blockIdx.x * 256;          // 4 nodes per block
  xs[tid] = xin[base + tid];
  __syncthreads();
  int r = tid >> 6, j = tid & 63;
  float acc = nb[j];
#pragma unroll
  for (int t = 0; t < 64; t++) acc = fmaf(xs[r * 64 + t], nw[t * 64 + j], acc);
  x[base + tid] = acc;
}

__global__ void count_kernel(const int* __restrict__ dst, int* __restrict__ cnt)
{
  int e = blockIdx.x * 256 + threadIdx.x;   // grid exactly covers E
  atomicAdd(&cnt[dst[e]], 1);
}

__global__ __launch_bounds__(256) void scan_a_kernel(
    const int* __restrict__ cnt, int* __restrict__ bsum)
{
  __shared__ int s[256];
  int i = blockIdx.x * 256 + threadIdx.x;
  s[threadIdx.x] = (i < N_NODES) ? cnt[i] : 0;
  __syncthreads();
  for (int off = 128; off > 0; off >>= 1) {
    if (threadIdx.x < off) s[threadIdx.x] += s[threadIdx.x + off];
    __syncthreads();
  }
  if (threadIdx.x == 0) bsum[blockIdx.x] = s[0];
}

__global__ __launch_bounds__(256) void scan_b_kernel(
    const int* __restrict__ bsum, int* __restrict__ boff)
{
  __shared__ int s[256];
  int tid = threadIdx.x;
  int v = (tid < 196) ? bsum[tid] : 0;
  s[tid] = v;
  __syncthreads();
  for (int off = 1; off < 256; off <<= 1) {
    int t = (tid >= off) ? s[tid - off] : 0;
    __syncthreads();
    s[tid] += t;
    __syncthreads();
  }
  boff[tid] = s[tid] - v;   // exclusive prefix of block sums
}

__global__ __launch_bounds__(256) void scan_c_kernel(
    const int* __restrict__ cnt, const int* __restrict__ boff,
    int* __restrict__ row_ptr)
{
  __shared__ int s[256];
  int tid = threadIdx.x;
  int i = blockIdx.x * 256 + tid;
  int v = (i < N_NODES) ? cnt[i] : 0;
  s[tid] = v;
  __syncthreads();
  for (int off = 1; off < 256; off <<= 1) {
    int t = (tid >= off) ? s[tid - off] : 0;
    __syncthreads();
    s[tid] += t;
    __syncthreads();
  }
  int incl = s[tid];
  int base = boff[blockIdx.x];
  if (i < N_NODES) row_ptr[i] = base + incl - v;
  if (i == N_NODES - 1) row_ptr[N_NODES] = base + incl;
}

__global__ void fill_kernel(const int* __restrict__ src, const int* __restrict__ dst,
                            int* __restrict__ cursor, int* __restrict__ srcs,
                            int* __restrict__ eids)
{
  int e = blockIdx.x * 256 + threadIdx.x;
  int d = dst[e];
  int pos = atomicAdd(&cursor[d], 1);
  srcs[pos] = src[e];
  eids[pos] = e;
}

__global__ __launch_bounds__(256) void deg_log_kernel(
    const int* __restrict__ cnt, float* __restrict__ log_deg,
    double* __restrict__ avgacc)
{
  __shared__ double sb[256];
  int i = blockIdx.x * 256 + threadIdx.x;
  double c = 0.0;
  if (i < N_NODES) {
    int d = cnt[i];
    int dc = d > 0 ? d : 1;
    log_deg[i] = logf((float)dc + 1.0f);         // log(degc + 1)
    c = (double)logf((float)d + 1.0f);           // avg uses raw deg
  }
  sb[threadIdx.x] = c;
  __syncthreads();
  for (int off = 128; off > 0; off >>= 1) {
    if (threadIdx.x < off) sb[threadIdx.x] += sb[threadIdx.x + off];
    __syncthreads();
  }
  if (threadIdx.x == 0) atomicAdd(avgacc, sb[0]);
}

__global__ void finalize_avg_kernel(const double* __restrict__ avgacc,
                                    float* __restrict__ avgf)
{
  *avgf = (float)(*avgacc / (double)N_NODES);
}

// graph node counts from sorted batch via binary search
__global__ void gbound_kernel(const int* __restrict__ batch, int* __restrict__ gcnt)
{
  __shared__ int sb[65];
  int g = threadIdx.x;  // 64 threads
  int lo = 0, hi = N_NODES;
  while (lo < hi) { int mid = (lo + hi) >> 1; if (batch[mid] < g) lo = mid + 1; else hi = mid; }
  sb[g] = lo;
  if (g == 0) sb[64] = N_NODES;
  __syncthreads();
  gcnt[g] = sb[g + 1] - sb[g];
}

// ===================== weight prep: fold + transpose + bf16 hi/lo split =====

__global__ __launch_bounds__(256) void wprep_kernel(
    const float* __restrict__ conv_w, unsigned short* __restrict__ wh,
    unsigned short* __restrict__ wl)
{
  int idx = blockIdx.x * 256 + threadIdx.x;   // 3*192*576 = 331776 = 1296*256
  int k = idx % 576;
  int c = (idx / 576) % 192;
  int l = idx / (576 * 192);
  int s = c >> 6, j = c & 63;
  const float* CW = conv_w + (size_t)l * 2304 * 64;
  float v;
  if (k < 64) {
    int base = s * 768 + k;
    v = CW[base * 64 + j] + CW[(base + 192) * 64 + j] + CW[(base + 384) * 64 + j];
  } else {
    const int srcseg[8] = {1, 2, 4, 5, 7, 8, 10, 11};
    int q = (k >> 6) - 1;
    int t = k & 63;
    v = CW[(s * 768 + srcseg[q] * 64 + t) * 64 + j];
  }
  unsigned short hh = f2bf_rne(v);
  wh[idx] = hh;
  wl[idx] = f2bf_rne(v - bf2f(hh));
}

__global__ void bprep_kernel(const float* __restrict__ conv_w, float* __restrict__ beff)
{
  int l = blockIdx.x;                 // 3 blocks x 192 threads
  int s = threadIdx.x >> 6, j = threadIdx.x & 63;
  const float* CW = conv_w + (size_t)l * 2304 * 64 + (size_t)(s * 768 + 576) * 64;
  float sum = 0.f;
#pragma unroll
  for (int t = 0; t < 64; t++) sum += CW[t * 64 + j];
  beff[(l * 3 + s) * 64 + j] = sum * 0.0031622776601683794f;   // sqrt(1e-5)
}

// ===================== e-segment aggregation via MFMA encoder ===============
// One wave per node. Per 16-edge CSR tile: A = attrs [16 edges x 16 attrs]
// (K-padded to 32: quads 2-3 zero), B = edge_w [16 x 64] in 4 col-blocks.
// 3-product split-bf16 MFMA computes ea for the tile; stats accumulate from
// the C-layout (col=lane&15, row=quad*4+reg). Pad rows clamp to the node's
// last edge (max/min-safe duplicates); sum/sumsq mask invalid rows.

__global__ __launch_bounds__(256) void agg_e_kernel(
    const float* __restrict__ eattr, const float* __restrict__ edge_w,
    const float* __restrict__ edge_b, const int* __restrict__ row_ptr,
    const int* __restrict__ eids,
    unsigned short* __restrict__ agg_h, unsigned short* __restrict__ agg_l)
{
  int lane = threadIdx.x & 63;
  int quad = lane >> 4, l15 = lane & 15;
  int n = blockIdx.x * 4 + (threadIdx.x >> 6);
  if (n >= N_NODES) return;

  // B fragments (once per wave): block b covers cols b*16..b*16+15
  bf16x8 Bh[4], Bl[4];
  float ebc[4];
#pragma unroll
  for (int b = 0; b < 4; b++) {
    float wv[8];
#pragma unroll
    for (int j = 0; j < 8; j++) {
      int k = quad * 8 + j;
      wv[j] = (k < 16) ? edge_w[k * 64 + b * 16 + l15] : 0.f;
    }
    split8(wv, Bh[b], Bl[b]);
    ebc[b] = edge_b[b * 16 + l15];
  }

  int s0 = row_ptr[n], s1 = row_ptr[n + 1];
  int deg = s1 - s0;
  float sum[4] = {}, sq[4] = {};
  float mx[4] = {-3.4e38f, -3.4e38f, -3.4e38f, -3.4e38f};
  float mn[4] = {3.4e38f, 3.4e38f, 3.4e38f, 3.4e38f};

  for (int t0 = s0; t0 < s1; t0 += 16) {
    int pos = t0 + l15;
    if (pos >= s1) pos = s1 - 1;            // clamp pad rows to last edge
    int eid = eids[pos];
    bf16x8 Ah, Al;
    if (quad < 2) {
      float a[8];
      const float4* ap = (const float4*)(eattr + (size_t)eid * 16 + quad * 8);
      float4 f0 = ap[0], f1 = ap[1];
      a[0] = f0.x; a[1] = f0.y; a[2] = f0.z; a[3] = f0.w;
      a[4] = f1.x; a[5] = f1.y; a[6] = f1.z; a[7] = f1.w;
      split8(a, Ah, Al);
    } else {
      U8 z; z.u[0] = z.u[1] = z.u[2] = z.u[3] = 0;
      Ah = z.v; Al = z.v;
    }
    f32x4 C[4] = {};
#pragma unroll
    for (int b = 0; b < 4; b++) {
      C[b] = __builtin_amdgcn_mfma_f32_16x16x32_bf16(Ah, Bh[b], C[b], 0, 0, 0);
      C[b] = __builtin_amdgcn_mfma_f32_16x16x32_bf16(Al, Bh[b], C[b], 0, 0, 0);
      C[b] = __builtin_amdgcn_mfma_f32_16x16x32_bf16(Ah, Bl[b], C[b], 0, 0, 0);
    }
#pragma unroll
    for (int r = 0; r < 4; r++) {
      bool rv = (t0 + quad * 4 + r) < s1;
#pragma unroll
      for (int b = 0; b < 4; b++) {
        float v = C[b][r] + ebc[b];
        float vm = rv ? v : 0.f;
        sum[b] += vm; sq[b] = fmaf(vm, vm, sq[b]);
        mx[b] = fmaxf(mx[b], v); mn[b] = fminf(mn[b], v);
      }
    }
  }

  // cross-quad reduce (lanes 16 apart share the same col within a block)
#pragma unroll
  for (int b = 0; b < 4; b++) {
    sum[b] += __shfl_xor(sum[b], 16, 64); sum[b] += __shfl_xor(sum[b], 32, 64);
    sq[b]  += __shfl_xor(sq[b], 16, 64);  sq[b]  += __shfl_xor(sq[b], 32, 64);
    mx[b] = fmaxf(mx[b], __shfl_xor(mx[b], 16, 64));
    mx[b] = fmaxf(mx[b], __shfl_xor(mx[b], 32, 64));
    mn[b] = fminf(mn[b], __shfl_xor(mn[b], 16, 64));
    mn[b] = fminf(mn[b], __shfl_xor(mn[b], 32, 64));
  }
  // this lane's output col = quad*16 + l15 = lane -> select block b = quad
  float S  = quad == 0 ? sum[0] : quad == 1 ? sum[1] : quad == 2 ? sum[2] : sum[3];
  float Q  = quad == 0 ? sq[0]  : quad == 1 ? sq[1]  : quad == 2 ? sq[2]  : sq[3];
  float MX = quad == 0 ? mx[0]  : quad == 1 ? mx[1]  : quad == 2 ? mx[2]  : mx[3];
  float MN = quad == 0 ? mn[0]  : quad == 1 ? mn[1]  : quad == 2 ? mn[2]  : mn[3];

  float inv = 1.0f / fmaxf((float)deg, 1.0f);
  bool has = deg > 0;
  float m_e = S * inv, ms_e = Q * inv;
  float sd_e = sqrtf(fmaxf(ms_e - m_e * m_e, 0.f) + 1e-5f);
  float mx_e = has ? MX : 0.f, mn_e = has ? MN : 0.f;

  unsigned short* bh = agg_h + (size_t)n * KEFF;
  unsigned short* bl = agg_l + (size_t)n * KEFF;
#define W2(off, val) { float _v = (val); unsigned short _h = f2bf_rne(_v); \
                       bh[(off) + lane] = _h; bl[(off) + lane] = f2bf_rne(_v - bf2f(_h)); }
  W2(128, m_e); W2(256, mn_e); W2(384, mx_e); W2(512, sd_e);
#undef W2
}

// ===================== per-layer x-segment aggregation =====================
// x8 unroll: 8 gathers in flight, 4 rotating accumulator chains.

__global__ __launch_bounds__(256) void agg_x_kernel(
    const float* __restrict__ x, const int* __restrict__ srcs,
    const int* __restrict__ row_ptr,
    unsigned short* __restrict__ agg_h, unsigned short* __restrict__ agg_l)
{
  int lane = threadIdx.x & 63;
  int n = blockIdx.x * 4 + (threadIdx.x >> 6);
  if (n >= N_NODES) return;
  float xd = x[(size_t)n * 64 + lane];
  int s0 = row_ptr[n], s1 = row_ptr[n + 1];
  float sA = 0.f, sB = 0.f, sC = 0.f, sD = 0.f;
  float qA = 0.f, qB = 0.f, qC = 0.f, qD = 0.f;
  float mx0 = -3.4e38f, mx1 = -3.4e38f, mn0 = 3.4e38f, mn1 = 3.4e38f;
  int j = s0;
  for (; j + 7 < s1; j += 8) {
    int e0 = srcs[j],     e1 = srcs[j + 1], e2 = srcs[j + 2], e3 = srcs[j + 3];
    int e4 = srcs[j + 4], e5 = srcs[j + 5], e6 = srcs[j + 6], e7 = srcs[j + 7];
    float x0 = x[(size_t)e0 * 64 + lane];
    float x1 = x[(size_t)e1 * 64 + lane];
    float x2 = x[(size_t)e2 * 64 + lane];
    float x3 = x[(size_t)e3 * 64 + lane];
    float x4 = x[(size_t)e4 * 64 + lane];
    float x5 = x[(size_t)e5 * 64 + lane];
    float x6 = x[(size_t)e6 * 64 + lane];
    float x7 = x[(size_t)e7 * 64 + lane];
    sA += x0; sB += x1; sC += x2; sD += x3;
    sA += x4; sB += x5; sC += x6; sD += x7;
    qA = fmaf(x0, x0, qA); qB = fmaf(x1, x1, qB);
    qC = fmaf(x2, x2, qC); qD = fmaf(x3, x3, qD);
    qA = fmaf(x4, x4, qA); qB = fmaf(x5, x5, qB);
    qC = fmaf(x6, x6, qC); qD = fmaf(x7, x7, qD);
    mx0 = fmaxf(mx0, fmaxf(fmaxf(x0, x1), fmaxf(x2, x3)));
    mx1 = fmaxf(mx1, fmaxf(fmaxf(x4, x5), fmaxf(x6, x7)));
    mn0 = fminf(mn0, fminf(fminf(x0, x1), fminf(x2, x3)));
    mn1 = fminf(mn1, fminf(fminf(x4, x5), fminf(x6, x7)));
  }
  for (; j + 3 < s1; j += 4) {
    int e0 = srcs[j], e1 = srcs[j + 1], e2 = srcs[j + 2], e3 = srcs[j + 3];
    float x0 = x[(size_t)e0 * 64 + lane];
    float x1 = x[(size_t)e1 * 64 + lane];
    float x2 = x[(size_t)e2 * 64 + lane];
    float x3 = x[(size_t)e3 * 64 + lane];
    sA += x0; sB += x1; sC += x2; sD += x3;
    qA = fmaf(x0, x0, qA); qB = fmaf(x1, x1, qB);
    qC = fmaf(x2, x2, qC); qD = fmaf(x3, x3, qD);
    mx0 = fmaxf(mx0, fmaxf(x0, x1)); mx1 = fmaxf(mx1, fmaxf(x2, x3));
    mn0 = fminf(mn0, fminf(x0, x1)); mn1 = fminf(mn1, fminf(x2, x3));
  }
  for (; j < s1; j++) {
    float xa = x[(size_t)srcs[j] * 64 + lane];
    sA += xa; qA = fmaf(xa, xa, qA);
    mx0 = fmaxf(mx0, xa); mn0 = fminf(mn0, xa);
  }
  float sx = (sA + sB) + (sC + sD);
  float qx = (qA + qB) + (qC + qD);
  float mxx = fmaxf(mx0, mx1), mnx = fminf(mn0, mn1);

  int deg = s1 - s0;
  float inv = 1.0f / fmaxf((float)deg, 1.0f);
  bool has = deg > 0;
  float m_s = sx * inv, ms_s = qx * inv;
  float sd_s = sqrtf(fmaxf(ms_s - m_s * m_s, 0.f) + 1e-5f);
  float mx_s = has ? mxx : 0.f, mn_s = has ? mnx : 0.f;

  unsigned short* bh = agg_h + (size_t)n * KEFF;
  unsigned short* bl = agg_l + (size_t)n * KEFF;
#define W2(off, val) { float _v = (val); unsigned short _h = f2bf_rne(_v); \
                       bh[(off) + lane] = _h; bl[(off) + lane] = f2bf_rne(_v - bf2f(_h)); }
  W2(0,   has ? xd : 0.f);
  W2(64,  m_s); W2(192, mn_s); W2(320, mx_s); W2(448, sd_s);
#undef W2
}

// ===================== MFMA GEMM + fused BN stats =====================
// D = Ah*Bh + Al*Bh + Ah*Bl (split-bf16 ~ fp32). 256 thr / 4 waves, M=64,
// N=192. C/D layout: col=lane&15, row=quad*4+reg -> amp/att combine intra-lane.

__global__ __launch_bounds__(256, 3) void gemm_kernel(
    const unsigned short* __restrict__ Ah, const unsigned short* __restrict__ Al,
    const unsigned short* __restrict__ Wh, const unsigned short* __restrict__ Wl,
    const float* __restrict__ beff, const float* __restrict__ bias,
    const float* __restrict__ log_deg, const float* __restrict__ avg_ptr,
    float* __restrict__ h, double* __restrict__ bnacc)
{
  __shared__ __align__(16) short AsH[64 * 40], AsL[64 * 40];
  __shared__ __align__(16) short BsH[192 * 40], BsL[192 * 40];
  int tid = threadIdx.x;
  int lane = tid & 63, w = tid >> 6;
  int quad = lane >> 4, l15 = lane & 15;
  int n0 = blockIdx.x * 64;

  int arow = tid >> 2, ac = tid & 3;
  int an = n0 + arow; if (an >= N_NODES) an = N_NODES - 1;
  const unsigned short* gah = Ah + (size_t)an * KEFF + ac * 8;
  const unsigned short* gal = Al + (size_t)an * KEFF + ac * 8;

  f32x4 acc[4][3] = {};

  for (int k0 = 0; k0 < KEFF; k0 += 32) {
    *(float4*)(AsH + arow * 40 + ac * 8) = *(const float4*)(gah + k0);
    *(float4*)(AsL + arow * 40 + ac * 8) = *(const float4*)(gal + k0);
#pragma unroll
    for (int q = 0; q < 6; q++) {
      int r = tid + (q < 3 ? q : q - 3) * 256;          // 0..767
      int col = r >> 2, cc = r & 3;
      const unsigned short* gb = (q < 3) ? Wh : Wl;
      short* bs = (q < 3) ? BsH : BsL;
      *(float4*)(bs + col * 40 + cc * 8) =
          *(const float4*)(gb + (size_t)col * KEFF + k0 + cc * 8);
    }
    __syncthreads();

    bf16x8 bh[3], bl[3];
#pragma unroll
    for (int s = 0; s < 3; s++) {
      int col = s * 64 + w * 16 + l15;
      bh[s] = *(const bf16x8*)(BsH + col * 40 + quad * 8);
      bl[s] = *(const bf16x8*)(BsL + col * 40 + quad * 8);
    }
#pragma unroll
    for (int i = 0; i < 4; i++) {
      int row = i * 16 + l15;
      bf16x8 ah = *(const bf16x8*)(AsH + row * 40 + quad * 8);
      bf16x8 al = *(const bf16x8*)(AsL + row * 40 + quad * 8);
#pragma unroll
      for (int s = 0; s < 3; s++) {
        acc[i][s] = __builtin_amdgcn_mfma_f32_16x16x32_bf16(ah, bh[s], acc[i][s], 0, 0, 0);
        acc[i][s] = __builtin_amdgcn_mfma_f32_16x16x32_bf16(al, bh[s], acc[i][s], 0, 0, 0);
        acc[i][s] = __builtin_amdgcn_mfma_f32_16x16x32_bf16(ah, bl[s], acc[i][s], 0, 0, 0);
      }
    }
    __syncthreads();
  }

  float avg = *avg_ptr;
  int col = w * 16 + l15;
  float be0 = beff[col], be1 = beff[64 + col], be2 = beff[128 + col];
  float bi = bias[col];
  float ss = 0.f, sq = 0.f;
#pragma unroll
  for (int i = 0; i < 4; i++) {
#pragma unroll
    for (int r = 0; r < 4; r++) {
      int n = n0 + i * 16 + quad * 4 + r;
      if (n < N_NODES) {
        float ld = log_deg[n];
        float amp = ld / avg, att = avg / ld;
        float v = (acc[i][0][r] + be0) + amp * (acc[i][1][r] + be1)
                + att * (acc[i][2][r] + be2) + bi;
        h[(size_t)n * 64 + col] = v;
        ss += v; sq = fmaf(v, v, sq);
      }
    }
  }
  // reduce over quads (same col every 16 lanes)
  ss += __shfl_xor(ss, 16, 64); ss += __shfl_xor(ss, 32, 64);
  sq += __shfl_xor(sq, 16, 64); sq += __shfl_xor(sq, 32, 64);
  if (quad == 0) {
    atomicAdd(&bnacc[col], (double)ss);
    atomicAdd(&bnacc[64 + col], (double)sq);
  }
}

// ===================== BatchNorm finalize + apply =====================

__global__ void bn_finalize_kernel(const double* __restrict__ accS,
                                   const double* __restrict__ accQ,
                                   const float* __restrict__ g,
                                   float* __restrict__ muf, float* __restrict__ scf)
{
  int j = threadIdx.x;  // 64 threads
  double mu = accS[j] / (double)N_NODES;
  double var = accQ[j] / (double)N_NODES - mu * mu;
  double rstd = 1.0 / sqrt(var + 1e-5);
  muf[j] = (float)mu;
  scf[j] = (float)(rstd * (double)g[j]);
}

__global__ __launch_bounds__(256) void apply_kernel(
    const float* __restrict__ h, const float* __restrict__ muf,
    const float* __restrict__ scf, const float* __restrict__ bnb,
    float* __restrict__ x)
{
  int i4 = blockIdx.x * 256 + threadIdx.x;   // float4 index, exact grid
  const float4* h4 = (const float4*)h;
  float4* x4 = (float4*)x;
  int c4 = i4 & 15;
  float4 hv = h4[i4], xv = x4[i4];
  float4 mu = ((const float4*)muf)[c4];
  float4 sc = ((const float4*)scf)[c4];
  float4 bb = ((const float4*)bnb)[c4];
  float4 r;
  r.x = fmaxf((hv.x - mu.x) * sc.x + bb.x, 0.f) + xv.x;
  r.y = fmaxf((hv.y - mu.y) * sc.y + bb.y, 0.f) + xv.y;
  r.z = fmaxf((hv.z - mu.z) * sc.z + bb.z, 0.f) + xv.z;
  r.w = fmaxf((hv.w - mu.w) * sc.w + bb.w, 0.f) + xv.w;
  x4[i4] = r;
}

// ===================== pooling + head =====================

__global__ __launch_bounds__(256) void pool_kernel(
    const float* __restrict__ x, const int* __restrict__ batch,
    float* __restrict__ gsum)
{
  int tid = threadIdx.x;
  int j = tid & 63, ri = tid >> 6;
  float acc = 0.f; int cur = -1;
  for (int k = 0; k < 16; k++) {
    int n = blockIdx.x * 64 + k * 4 + ri;
    if (n < N_NODES) {
      int b = batch[n];
      if (b != cur) {
        if (cur >= 0) atomicAdd(&gsum[cur * 64 + j], acc);
        cur = b; acc = 0.f;
      }
      acc += x[(size_t)n * 64 + j];
    }
  }
  if (cur >= 0) atomicAdd(&gsum[cur * 64 + j], acc);
}

__global__ void fc_kernel(const float* __restrict__ gsum, const int* __restrict__ gcnt,
                          const float* __restrict__ w1, const float* __restrict__ b1,
                          const float* __restrict__ w2, const float* __restrict__ b2,
                          const float* __restrict__ w3, const float* __restrict__ b3,
                          float* __restrict__ out)
{
  int g = threadIdx.x;  // 64 threads, one per graph
  float cnt = fmaxf((float)gcnt[g], 1.0f);
  float gv[64];
#pragma unroll
  for (int j = 0; j < 64; j++) gv[j] = gsum[g * 64 + j] / cnt;
  float a1[32];
#pragma unroll
  for (int o = 0; o < 32; o++) {
    float s = b1[o];
#pragma unroll
    for (int j = 0; j < 64; j++) s = fmaf(gv[j], w1[j * 32 + o], s);
    a1[o] = fmaxf(s, 0.f);
  }
  float a2[16];
#pragma unroll
  for (int o = 0; o < 16; o++) {
    float s = b2[o];
#pragma unroll
    for (int j = 0; j < 32; j++) s = fmaf(a1[j], w2[j * 16 + o], s);
    a2[o] = fmaxf(s, 0.f);
  }
#pragma unroll
  for (int o = 0; o < 10; o++) {
    float s = b3[o];
#pragma unroll
    for (int j = 0; j < 16; j++) s = fmaf(a2[j], w3[j * 10 + o], s);
    out[g * 10 + o] = s;
  }
}

// ===================== launch =====================

extern "C" void kernel_launch(void* const* d_in, const int* in_sizes, int n_in,
                              void* d_out, int out_size, void* d_ws, size_t ws_size,
                              hipStream_t stream)
{
  (void)in_sizes; (void)n_in; (void)out_size; (void)ws_size;
  const float* xin    = (const float*)d_in[0];
  const int*   ei     = (const int*)d_in[1];
  const int*   batch  = (const int*)d_in[2];
  const float* eattr  = (const float*)d_in[3];
  const float* node_w = (const float*)d_in[4];
  const float* node_b = (const float*)d_in[5];
  const float* edge_w = (const float*)d_in[6];
  const float* edge_b = (const float*)d_in[7];
  const float* conv_w = (const float*)d_in[8];
  const float* conv_b = (const float*)d_in[9];
  const float* bn_g   = (const float*)d_in[10];
  const float* bn_b   = (const float*)d_in[11];
  const float* fc1_w  = (const float*)d_in[12];
  const float* fc1_b  = (const float*)d_in[13];
  const float* fc2_w  = (const float*)d_in[14];
  const float* fc2_b  = (const float*)d_in[15];
  const float* fc3_w  = (const float*)d_in[16];
  const float* fc3_b  = (const float*)d_in[17];
  float* out = (float*)d_out;
  const int* srcp = ei;
  const int* dstp = ei + N_EDGES;

  char* p = (char*)d_ws;
  auto alloc = [&](size_t b) { char* r = p; p += (b + 255) & ~(size_t)255; return (void*)r; };
  float*  x       = (float*)alloc((size_t)N_NODES * 64 * 4);
  float*  h       = (float*)alloc((size_t)N_NODES * 64 * 4);
  unsigned short* agg_h = (unsigned short*)alloc((size_t)N_NODES * KEFF * 2);
  unsigned short* agg_l = (unsigned short*)alloc((size_t)N_NODES * KEFF * 2);
  unsigned short* wh    = (unsigned short*)alloc((size_t)3 * 192 * KEFF * 2);
  unsigned short* wl    = (unsigned short*)alloc((size_t)3 * 192 * KEFF * 2);
  int*    srcs    = (int*)alloc((size_t)N_EDGES * 4);
  int*    eids    = (int*)alloc((size_t)N_EDGES * 4);
  float*  beff    = (float*)alloc((size_t)3 * 3 * 64 * 4);
  int*    row_ptr = (int*)alloc((N_NODES + 1) * 4);
  int*    cursor  = (int*)alloc((size_t)N_NODES * 4);
  int*    cnt     = (int*)alloc((size_t)N_NODES * 4);
  float*  log_deg = (float*)alloc((size_t)N_NODES * 4);
  int*    bsum    = (int*)alloc(256 * 4);
  int*    boff    = (int*)alloc(256 * 4);
  double* avgacc  = (double*)alloc(256);
  float*  avgf    = (float*)alloc(256);
  double* bnacc   = (double*)alloc(3 * 128 * 8);
  float*  muf     = (float*)alloc(256);
  float*  scf     = (float*)alloc(256);
  float*  gsum    = (float*)alloc((size_t)NGRAPH * 64 * 4);
  int*    gcnt    = (int*)alloc((size_t)NGRAPH * 4);

  hipMemsetAsync(cnt, 0, (size_t)N_NODES * 4, stream);
  hipMemsetAsync(avgacc, 0, 8, stream);
  hipMemsetAsync(gsum, 0, (size_t)NGRAPH * 64 * 4, stream);
  hipMemsetAsync(bnacc, 0, 3 * 128 * 8, stream);

  node_enc_kernel<<<12500, 256, 0, stream>>>(xin, node_w, node_b, x);
  count_kernel<<<3125, 256, 0, stream>>>(dstp, cnt);
  scan_a_kernel<<<196, 256, 0, stream>>>(cnt, bsum);
  scan_b_kernel<<<1, 256, 0, stream>>>(bsum, boff);
  scan_c_kernel<<<196, 256, 0, stream>>>(cnt, boff, row_ptr);
  hipMemcpyAsync(cursor, row_ptr, (size_t)N_NODES * 4, hipMemcpyDeviceToDevice, stream);
  fill_kernel<<<3125, 256, 0, stream>>>(srcp, dstp, cursor, srcs, eids);
  deg_log_kernel<<<196, 256, 0, stream>>>(cnt, log_deg, avgacc);
  finalize_avg_kernel<<<1, 1, 0, stream>>>(avgacc, avgf);
  gbound_kernel<<<1, 64, 0, stream>>>(batch, gcnt);
  wprep_kernel<<<1296, 256, 0, stream>>>(conv_w, wh, wl);
  bprep_kernel<<<3, 192, 0, stream>>>(conv_w, beff);

  agg_e_kernel<<<12500, 256, 0, stream>>>(eattr, edge_w, edge_b, row_ptr,
                                          eids, agg_h, agg_l);

  for (int l = 0; l < 3; l++) {
    agg_x_kernel<<<12500, 256, 0, stream>>>(x, srcs, row_ptr, agg_h, agg_l);
    gemm_kernel<<<782, 256, 0, stream>>>(agg_h, agg_l,
                                         wh + (size_t)l * 192 * KEFF,
                                         wl + (size_t)l * 192 * KEFF,
                                         beff + l * 192, conv_b + l * 64,
                                         log_deg, avgf, h, bnacc + l * 128);
    bn_finalize_kernel<<<1, 64, 0, stream>>>(bnacc + l * 128, bnacc + l * 128 + 64,
                                             bn_g + l * 64, muf, scf);
    apply_kernel<<<3125, 256, 0, stream>>>(h, muf, scf, bn_b + l * 64, x);
  }

  pool_kernel<<<782, 256, 0, stream>>>(x, batch, gsum);
  fc_kernel<<<1, 64, 0, stream>>>(gsum, gcnt, fc1_w, fc1_b, fc2_w, fc2_b,
                                  fc3_w, fc3_b, out);
}